// Round 7
// baseline (283.647 us; speedup 1.0000x reference)
//
#include <hip/hip_runtime.h>
#include <hip/hip_bf16.h>
#include <math.h>

#define B_ 4
#define T_ 2048
#define C_ 1024
#define H_ 16
#define D_ 64

typedef __attribute__((ext_vector_type(8))) short bf16x8_t;   // 8 bf16 (4 VGPRs)
typedef __attribute__((ext_vector_type(4))) float f32x4_t;
typedef __attribute__((ext_vector_type(2))) unsigned int uiv2_t;

// q is pre-scaled by 0.125*log2(e) in the QKV epilogue, so scores arrive in
// base-2: p = exp2(s' - SHIFT2). |s|<=~8 => |s'|<=11.6; SHIFT2=32 keeps
// everything finite-positive; normalization cancels the shift exactly.
// The -SHIFT2 bias rides in as the C-operand of the first MFMA of each chain.
#define SHIFT2 32.0f

// async global->LDS DMA, 16B/lane; HW dest = wave-uniform lds base + lane*16
#define GLOAD_LDS16(gp, lp)                                                          \
    __builtin_amdgcn_global_load_lds(                                                \
        (const __attribute__((address_space(1))) void*)(gp),                         \
        (__attribute__((address_space(3))) void*)(lp), 16, 0, 0)

// compiler-only ordering (no instruction): per-wave LDS RAW relies on the
// in-order DS pipe (verified correct rounds 6-7)
#define WAVE_ORDER() __builtin_amdgcn_wave_barrier()

__device__ inline short bf16bits(float f) {
    __hip_bfloat16 h = __float2bfloat16(f);
    return *reinterpret_cast<short*>(&h);
}

__device__ inline unsigned int pack2bf(float a, float b) {
    __hip_bfloat162 h = __float22bfloat162_rn(make_float2(a, b));  // v_cvt_pk_bf16_f32
    return *reinterpret_cast<unsigned int*>(&h);
}

// ---------------------------------------------------------------------------
__global__ void xconv_kernel(const float* __restrict__ in,
                             __hip_bfloat16* __restrict__ out, int n4) {
    int i = blockIdx.x * blockDim.x + threadIdx.x;
    if (i < n4) {
        float4 v = *(const float4*)(in + (size_t)i * 4);
        uint2 u;
        u.x = pack2bf(v.x, v.y);
        u.y = pack2bf(v.z, v.w);
        *(uint2*)(out + (size_t)i * 4) = u;
    }
}

// ---------------------------------------------------------------------------
// RoPE tables: tab[token][0..31]=cos, [32..63]=sin  (f32)
// ---------------------------------------------------------------------------
__global__ void rope_tab_kernel(const int* __restrict__ keep,
                                const int* __restrict__ orig,
                                float* __restrict__ tab) {
    int i = blockIdx.x * blockDim.x + threadIdx.x;   // token*32 + d
    int tok = i >> 5, d = i & 31;
    float freq = 0.5f * exp2f((float)d * (6.321928094887362f / 31.0f));
    float ang  = 6.283185307179586f * ((float)keep[tok] / (float)(*orig)) * freq;
    tab[(size_t)tok * 64 + d]      = cosf(ang);
    tab[(size_t)tok * 64 + 32 + d] = sinf(ang);
}

// ---------------------------------------------------------------------------
__global__ void transpose_conv_kernel(const float* __restrict__ in,
                                      __hip_bfloat16* __restrict__ out,
                                      int K, int N) {
    __shared__ float s[32][33];
    const int n0 = blockIdx.x * 32;
    const int k0 = blockIdx.y * 32;
    const int tx = threadIdx.x;
    const int ty = threadIdx.y;
#pragma unroll
    for (int yy = 0; yy < 32; yy += 8)
        s[ty + yy][tx] = in[(size_t)(k0 + ty + yy) * N + n0 + tx];
    __syncthreads();
#pragma unroll
    for (int yy = 0; yy < 32; yy += 8)
        out[(size_t)(n0 + ty + yy) * K + k0 + tx] = __float2bfloat16(s[tx][ty + yy]);
}

// ---------------------------------------------------------------------------
// GEMM 128x128 tile, BK=32, TRIPLE-BUFFERED global_load_lds staging with
// 2-deep counted-vmcnt pipeline (vmcnt(8): tiles t+1,t+2 in flight; the wait
// targets loads issued TWO iterations ago, covering ~900cy HBM latency).
// LDS XOR swizzle (T2, both-sides). XCD-CHUNKED block remap (T1): the HW
// round-robins blockIdx across 8 XCDs with private L2s; remapping
// swz=(bid&7)*(nwg/8)+(bid>>3) (bijective, nwg%8==0) gives each XCD a
// contiguous run of the GROUP_M-ordered blocks so A-panels/B-panels stay
// resident in that XCD's L2 (round-4 FETCH showed 4x A over-fetch).
// MODE 0: f32 store. MODE 1: qkv epilogue; V transposed through LDS.
// ---------------------------------------------------------------------------
#define GTILE (128 * 32)

template <int MODE>
__global__ __launch_bounds__(256)
void gemm_kernel(const __hip_bfloat16* __restrict__ A,
                 const __hip_bfloat16* __restrict__ BT,
                 const float* __restrict__ bias,
                 float* __restrict__ out,
                 __hip_bfloat16* __restrict__ qbuf,
                 __hip_bfloat16* __restrict__ kbuf,
                 __hip_bfloat16* __restrict__ vtbuf,
                 const float* __restrict__ ropetab,
                 int M, int N, int K) {
    // GS[0..3*GTILE): A triple-buffer; GS[3*GTILE..6*GTILE): B triple-buffer.
    __shared__ __align__(16) __hip_bfloat16 GS[6 * GTILE];

    const int tid  = threadIdx.x;
    const int lane = tid & 63;
    const int wave = tid >> 6;
    const int wm   = wave >> 1;
    const int wn   = wave & 1;
    const int l15  = lane & 15;
    const int quad = lane >> 4;

    // XCD-chunked bijective remap (nwg % 8 == 0 for both launches)
    const int nwg = gridDim.x;
    const int bid = (int)blockIdx.x;
    const int swz = (bid & 7) * (nwg >> 3) + (bid >> 3);

    const int nT  = N >> 7;
    const int grp = swz / (8 * nT);
    const int rem = swz - grp * 8 * nT;
    const int m0  = (grp * 8 + (rem & 7)) * 128;
    const int n0  = (rem >> 3) * 128;

    f32x4_t acc[4][4];
#pragma unroll
    for (int i = 0; i < 4; i++)
#pragma unroll
        for (int j = 0; j < 4; j++) acc[i][j] = (f32x4_t)0.0f;

    const int lrow = lane >> 2;
    // pre-swizzled source chunk: LDS[row][p] holds global chunk p^((row>>2)&3)
    const int scol = ((lane & 3) ^ ((lane >> 4) & 3)) * 8;
    const __hip_bfloat16* gA  = A  + (size_t)(m0 + wave * 16 + lrow) * K + scol;
    const __hip_bfloat16* gA2 = gA + (size_t)64 * K;
    const __hip_bfloat16* gB  = BT + (size_t)(n0 + wave * 16 + lrow) * K + scol;
    const __hip_bfloat16* gB2 = gB + (size_t)64 * K;
    const int ldsW = wave * 16 * 32;   // this wave's stage destination (elements)

    const int NK = K >> 5;
    // prologue: stage K-tiles 0 and 1 into buffers 0 and 1
    GLOAD_LDS16(gA,  GS + ldsW);
    GLOAD_LDS16(gA2, GS + ldsW + 64 * 32);
    GLOAD_LDS16(gB,  GS + 3 * GTILE + ldsW);
    GLOAD_LDS16(gB2, GS + 3 * GTILE + ldsW + 64 * 32);
    if (NK > 1) {
        GLOAD_LDS16(gA  + 32, GS + GTILE + ldsW);
        GLOAD_LDS16(gA2 + 32, GS + GTILE + ldsW + 64 * 32);
        GLOAD_LDS16(gB  + 32, GS + 3 * GTILE + GTILE + ldsW);
        GLOAD_LDS16(gB2 + 32, GS + 3 * GTILE + GTILE + ldsW + 64 * 32);
    }

    int off = 0;
    for (int t = 0; t < NK; ++t) {
        if (t + 2 < NK) {
            int poff = off + 2 * GTILE;
            if (poff >= 3 * GTILE) poff -= 3 * GTILE;
            const int kk = (t + 2) << 5;
            GLOAD_LDS16(gA  + kk, GS + poff + ldsW);
            GLOAD_LDS16(gA2 + kk, GS + poff + ldsW + 64 * 32);
            GLOAD_LDS16(gB  + kk, GS + 3 * GTILE + poff + ldsW);
            GLOAD_LDS16(gB2 + kk, GS + 3 * GTILE + poff + ldsW + 64 * 32);
            // leave only tiles t+1,t+2 (8 newest) in flight; tile t drained
            asm volatile("s_waitcnt vmcnt(8)" ::: "memory");
        } else if (t + 1 < NK) {
            asm volatile("s_waitcnt vmcnt(4)" ::: "memory");
        } else {
            asm volatile("s_waitcnt vmcnt(0)" ::: "memory");
        }
        __builtin_amdgcn_s_barrier();            // all waves' cur-tile DMA done
        __builtin_amdgcn_sched_barrier(0);       // pin: no ds_read hoists above

        bf16x8_t af[4], bfv[4];
#pragma unroll
        for (int i = 0; i < 4; i++)
            af[i] = *(const bf16x8_t*)(GS + off + (wm * 64 + i * 16 + l15) * 32 +
                                       ((quad ^ (l15 >> 2)) * 8));
#pragma unroll
        for (int j = 0; j < 4; j++)
            bfv[j] = *(const bf16x8_t*)(GS + 3 * GTILE + off + (wn * 64 + j * 16 + l15) * 32 +
                                        ((quad ^ (l15 >> 2)) * 8));
#pragma unroll
        for (int i = 0; i < 4; i++)
#pragma unroll
            for (int j = 0; j < 4; j++)
                acc[i][j] = __builtin_amdgcn_mfma_f32_16x16x32_bf16(af[i], bfv[j], acc[i][j], 0, 0, 0);

        __builtin_amdgcn_sched_barrier(0);       // pin: no ds_read sinks below
        asm volatile("s_waitcnt lgkmcnt(0)" ::: "memory");  // my LDS reads done
        __builtin_amdgcn_s_barrier();            // WAR: buffer reusable

        off += GTILE;
        if (off == 3 * GTILE) off = 0;
    }

    float bv[4];
#pragma unroll
    for (int j = 0; j < 4; j++)
        bv[j] = bias[n0 + wn * 64 + j * 16 + l15];

    if (MODE == 0) {
#pragma unroll
        for (int i = 0; i < 4; i++)
#pragma unroll
            for (int r = 0; r < 4; r++) {
                int row = m0 + wm * 64 + i * 16 + quad * 4 + r;
#pragma unroll
                for (int j = 0; j < 4; j++) {
                    int col = n0 + wn * 64 + j * 16 + l15;
                    out[(size_t)row * N + col] = acc[i][j][r] + bv[j];
                }
            }
    } else {
        const int cb   = n0 + wn * 64;
        const int part = cb >> 10;           // 0=q 1=k 2=v  (uniform per block)
        if (part == 2) {
            // transpose 128t x 128d(2 heads) through LDS (free after K-loop),
            // then coalesced 16B stores. Region per wn: 64 d-rows x 136 (pad).
            const int hb = (n0 & 1023) >> 6;     // head at wn=0; wn adds +1
            __hip_bfloat16* myL = GS + wn * (64 * 136);
#pragma unroll
            for (int j = 0; j < 4; j++)
#pragma unroll
                for (int i = 0; i < 4; i++)
#pragma unroll
                    for (int r = 0; r < 4; r++) {
                        int rt = wm * 64 + i * 16 + quad * 4 + r;   // token in tile
                        int d  = j * 16 + l15;
                        myL[d * 136 + rt] = __float2bfloat16(acc[i][j][r] + bv[j]);
                    }
            __syncthreads();
            const int bb  = m0 >> 11;
            const int t0  = m0 & 2047;
            const int row = tid >> 1;            // 0..127 = wn2*64 + d
            const int wn2 = row >> 6;
            const int dd  = row & 63;
            const __hip_bfloat16* src = GS + wn2 * (64 * 136) + dd * 136;
            __hip_bfloat16* dstv = vtbuf +
                ((size_t)((bb * H_ + hb + wn2) * D_ + dd)) * T_ + t0;
#pragma unroll
            for (int s = 0; s < 8; s++) {
                int ch = (tid & 1) * 8 + s;
                *(bf16x8_t*)(dstv + ch * 8) = *(const bf16x8_t*)(src + ch * 8);
            }
        } else {
            const int h = (cb & 1023) >> 6;
            __hip_bfloat16* dst = (part == 0) ? qbuf : kbuf;
            // q: fold 1/sqrt(D) AND log2(e) so attention uses exp2 directly
            const float sc = (part == 0) ? 0.18033688011112042f : 1.0f;
#pragma unroll
            for (int i = 0; i < 4; i++) {
#pragma unroll
                for (int r = 0; r < 4; r++) {
                    int row = m0 + wm * 64 + i * 16 + quad * 4 + r;
                    int b = row >> 11;
                    int t = row & 2047;
                    const float* trow = ropetab + (size_t)row * 64;
                    size_t base = ((size_t)(b * H_ + h) * T_ + t) * D_;
#pragma unroll
                    for (int j = 0; j < 2; j++) {
                        int d = j * 16 + l15;
                        float cs = trow[d];
                        float sn = trow[32 + d];
                        float x1 = acc[i][j][r]     + bv[j];
                        float x2 = acc[i][j + 2][r] + bv[j + 2];
                        dst[base + d]      = __float2bfloat16(sc * (x1 * cs - x2 * sn));
                        dst[base + d + 32] = __float2bfloat16(sc * (x1 * sn + x2 * cs));
                    }
                }
            }
        }
    }
}

// ---------------------------------------------------------------------------
// Flash attention v8 (REVERTED from v9's QBLK=64: halving resident waves
// 16->8/CU cost more in latency-hiding than the amortization gained —
// round-5 A/B: 87.2 vs 91.3 µs). QBLK=32/wave, 1024 blocks, 4 blocks/CU.
// Counted-vmcnt double-buffered K/V DMA, in-register P^T via permlane
// swaps, -SHIFT2 folded into MFMA C-in, setprio around MFMA clusters.
// ---------------------------------------------------------------------------
#define KVTILE (64 * 64)

__global__ __launch_bounds__(256, 4)
void attn_kernel(const __hip_bfloat16* __restrict__ q,
                 const __hip_bfloat16* __restrict__ k,
                 const __hip_bfloat16* __restrict__ vt,
                 __hip_bfloat16* __restrict__ attn_out) {
    // [0..1]*KVTILE: K double-buffer; [2..3]*KVTILE: V double-buffer (32 KB).
    // After the final barrier the front is reused as the per-wave epilogue
    // staging area (4 waves x 32 x 72 bf16 = 18 KB <= 32 KB).
    __shared__ __align__(16) __hip_bfloat16 SMEM[4 * KVTILE];

    const int tid  = threadIdx.x;
    const int lane = tid & 63;
    const int wave = tid >> 6;
    const int l15  = lane & 15;
    const int quad = lane >> 4;
    const int x7   = l15 & 7;

    const int bh = blockIdx.x & 63;          // XCD swizzle
    const int qt = blockIdx.x >> 6;          // 0..15
    const int b  = bh >> 4;
    const int h  = bh & 15;

    const size_t qkbase = (size_t)bh * T_ * D_;
    const size_t vbase  = (size_t)bh * D_ * T_;
    const int    qrow0  = qt * 128 + wave * 32;

    // DMA lane mapping: lane = drow*8 + dchunk; fetch global chunk dchunk^drow
    const int drow   = lane >> 3;        // 0..7
    const int gchunk = (lane & 7) ^ drow;

    const __hip_bfloat16* kg = k + qkbase;
    const __hip_bfloat16* vg = vt + vbase;

    // fragment-read swizzled chunk offsets (elements)
    const int c0 = ((quad)     ^ x7) * 8;
    const int c1 = ((4 + quad) ^ x7) * 8;

    // Q as B-fragment (n=qrow, k=d), direct global (once)
    bf16x8_t qa[2][2];
#pragma unroll
    for (int qf = 0; qf < 2; qf++)
#pragma unroll
        for (int kk = 0; kk < 2; kk++)
            qa[qf][kk] = *(const bf16x8_t*)(q + qkbase +
                          (size_t)(qrow0 + qf * 16 + l15) * D_ + kk * 32 + quad * 8);

    // all-ones A-fragment for MFMA row-sums
    bf16x8_t ones;
#pragma unroll
    for (int i = 0; i < 8; i++) ones[i] = (short)0x3F80;

    // loop-invariant C-operand: folds the -SHIFT2 softmax bias into the MFMA
    const f32x4_t mbias = (f32x4_t)(-SHIFT2);

    f32x4_t o[2][4];
#pragma unroll
    for (int qf = 0; qf < 2; qf++)
#pragma unroll
        for (int jd = 0; jd < 4; jd++) o[qf][jd] = (f32x4_t)0.0f;
    f32x4_t osum[2];
    osum[0] = (f32x4_t)0.0f;
    osum[1] = (f32x4_t)0.0f;

    // prologue: stage tile 0 into buffer 0 (iter-0 vmcnt+barrier syncs it)
#pragma unroll
    for (int i = 0; i < 2; i++) {
        int r = wave * 16 + i * 8;
        GLOAD_LDS16(kg + (size_t)(r + drow) * D_ + gchunk * 8, SMEM + r * 64);
        GLOAD_LDS16(vg + (size_t)(r + drow) * T_ + gchunk * 8, SMEM + 2 * KVTILE + r * 64);
    }

    for (int kt = 0; kt < T_ / 64; kt++) {
        const int curoff = (kt & 1) * KVTILE;
        const int nxtoff = curoff ^ KVTILE;
        // issue next tile's DMA FIRST; stays in flight across both barriers
        if (kt + 1 < T_ / 64) {
#pragma unroll
            for (int i = 0; i < 2; i++) {
                int r = wave * 16 + i * 8;
                GLOAD_LDS16(kg + (size_t)((kt + 1) * 64 + r + drow) * D_ + gchunk * 8,
                            SMEM + nxtoff + r * 64);
                GLOAD_LDS16(vg + (size_t)(r + drow) * T_ + (kt + 1) * 64 + gchunk * 8,
                            SMEM + 2 * KVTILE + nxtoff + r * 64);
            }
            // drain everything EXCEPT the 4 just-issued next-tile loads
            asm volatile("s_waitcnt vmcnt(4)" ::: "memory");
        } else {
            asm volatile("s_waitcnt vmcnt(0)" ::: "memory");
        }
        __builtin_amdgcn_s_barrier();            // all waves' cur-tile DMA done
        __builtin_amdgcn_sched_barrier(0);       // pin: no ds_read hoists above

        const __hip_bfloat16* KLc = SMEM + curoff;
        const __hip_bfloat16* VLc = SMEM + 2 * KVTILE + curoff;

        // K fragments (swizzled), then S^T = K.Q^T - SHIFT2 (bias via C-in)
        bf16x8_t kf[4][2];
#pragma unroll
        for (int jt = 0; jt < 4; jt++) {
            kf[jt][0] = *(const bf16x8_t*)(KLc + (jt * 16 + l15) * 64 + c0);
            kf[jt][1] = *(const bf16x8_t*)(KLc + (jt * 16 + l15) * 64 + c1);
        }

        f32x4_t sT[2][4];
        __builtin_amdgcn_s_setprio(1);
#pragma unroll
        for (int jt = 0; jt < 4; jt++)
#pragma unroll
            for (int qf = 0; qf < 2; qf++) {
                sT[qf][jt] = __builtin_amdgcn_mfma_f32_16x16x32_bf16(
                    kf[jt][0], qa[qf][0], mbias, 0, 0, 0);
                sT[qf][jt] = __builtin_amdgcn_mfma_f32_16x16x32_bf16(
                    kf[jt][1], qa[qf][1], sT[qf][jt], 0, 0, 0);
            }
        __builtin_amdgcn_s_setprio(0);

        // p = exp2(s'); pack to bf16 pairs, then build P^T B-fragments
        // entirely in registers via permlane swaps (no LDS round-trip).
        bf16x8_t pb[2][2];
#pragma unroll
        for (int qf = 0; qf < 2; qf++) {
            unsigned int w0[4], w1[4];
#pragma unroll
            for (int jt = 0; jt < 4; jt++) {
                float p0 = __builtin_amdgcn_exp2f(sT[qf][jt][0]);
                float p1 = __builtin_amdgcn_exp2f(sT[qf][jt][1]);
                float p2 = __builtin_amdgcn_exp2f(sT[qf][jt][2]);
                float p3 = __builtin_amdgcn_exp2f(sT[qf][jt][3]);
                w0[jt] = pack2bf(p0, p1);   // keys quad*4+0, +1
                w1[jt] = pack2bf(p2, p3);   // keys quad*4+2, +3
            }
#pragma unroll
            for (int kk = 0; kk < 2; kk++) {
                uiv2_t s0 = __builtin_amdgcn_permlane32_swap(w0[2 * kk], w0[2 * kk + 1], false, false);
                uiv2_t r0 = __builtin_amdgcn_permlane16_swap(s0[0], s0[1], false, false);
                uiv2_t s1 = __builtin_amdgcn_permlane32_swap(w1[2 * kk], w1[2 * kk + 1], false, false);
                uiv2_t r1 = __builtin_amdgcn_permlane16_swap(s1[0], s1[1], false, false);
                union { unsigned int u[4]; bf16x8_t v; } pu;
                pu.u[0] = r0[0];   // keys +0,1
                pu.u[1] = r1[0];   // keys +2,3
                pu.u[2] = r0[1];   // keys +4,5
                pu.u[3] = r1[1];   // keys +6,7
                pb[qf][kk] = pu.v;
            }
        }

        __builtin_amdgcn_s_setprio(1);
        // row-sums via ones-MFMA: every D row = sum_k P[n][k]
#pragma unroll
        for (int qf = 0; qf < 2; qf++) {
            osum[qf] = __builtin_amdgcn_mfma_f32_16x16x32_bf16(ones, pb[qf][0], osum[qf], 0, 0, 0);
            osum[qf] = __builtin_amdgcn_mfma_f32_16x16x32_bf16(ones, pb[qf][1], osum[qf], 0, 0, 0);
        }

        // o^T += V^T.P^T
#pragma unroll
        for (int jd = 0; jd < 4; jd++) {
            bf16x8_t vf0 = *(const bf16x8_t*)(VLc + (jd * 16 + l15) * 64 + c0);
            bf16x8_t vf1 = *(const bf16x8_t*)(VLc + (jd * 16 + l15) * 64 + c1);
#pragma unroll
            for (int qf = 0; qf < 2; qf++) {
                o[qf][jd] = __builtin_amdgcn_mfma_f32_16x16x32_bf16(vf0, pb[qf][0], o[qf][jd], 0, 0, 0);
                o[qf][jd] = __builtin_amdgcn_mfma_f32_16x16x32_bf16(vf1, pb[qf][1], o[qf][jd], 0, 0, 0);
            }
        }
        __builtin_amdgcn_s_setprio(0);

        __builtin_amdgcn_sched_barrier(0);       // pin: no ds_read sinks below
        asm volatile("s_waitcnt lgkmcnt(0)" ::: "memory");  // my LDS reads done
        __builtin_amdgcn_s_barrier();            // WAR: next iter may overwrite
    }

    // per-qrow inverse sums (all lanes/quads hold the value for their l15)
    float inv[2];
    inv[0] = 1.0f / osum[0][0];
    inv[1] = 1.0f / osum[1][0];

    // epilogue staging: reuse SMEM front (all K/V reads are behind the final
    // barrier above); per-wave private [32][72] bf16 region
    __hip_bfloat16* Pep = SMEM + wave * (32 * 72);

    WAVE_ORDER();
    // o^T -> LDS (packed b64), then coalesced 16B store
#pragma unroll
    for (int qf = 0; qf < 2; qf++) {
#pragma unroll
        for (int jd = 0; jd < 4; jd++) {
            uint2 pk;
            pk.x = pack2bf(o[qf][jd][0] * inv[qf], o[qf][jd][1] * inv[qf]);
            pk.y = pack2bf(o[qf][jd][2] * inv[qf], o[qf][jd][3] * inv[qf]);
            *(uint2*)(Pep + (qf * 16 + l15) * 72 + jd * 16 + quad * 4) = pk;
        }
    }
    WAVE_ORDER();

#pragma unroll
    for (int rnd = 0; rnd < 4; rnd++) {
        int row = rnd * 8 + (lane >> 3);
        int col = (lane & 7) * 8;
        bf16x8_t vrow = *(const bf16x8_t*)(Pep + row * 72 + col);
        int token = qt * 128 + wave * 32 + row;
        *(bf16x8_t*)(attn_out + ((size_t)(b * T_ + token)) * C_ + h * 64 + col) = vrow;
    }
}

// ---------------------------------------------------------------------------
extern "C" void kernel_launch(void* const* d_in, const int* in_sizes, int n_in,
                              void* d_out, int out_size, void* d_ws, size_t ws_size,
                              hipStream_t stream) {
    const float* x        = (const float*)d_in[0];
    const int*   keep_idx = (const int*)d_in[1];
    const int*   orig_len = (const int*)d_in[2];
    const float* Wqkv     = (const float*)d_in[3];
    const float* bqkv     = (const float*)d_in[4];
    const float* Wproj    = (const float*)d_in[5];
    const float* bproj    = (const float*)d_in[6];
    float*       out      = (float*)d_out;

    const size_t NTOK = (size_t)B_ * T_;
    const size_t QKV1 = NTOK * C_;

    __hip_bfloat16* qbuf    = (__hip_bfloat16*)d_ws;
    __hip_bfloat16* kbuf    = qbuf    + QKV1;
    __hip_bfloat16* vtbuf   = kbuf    + QKV1;
    __hip_bfloat16* attnbuf = vtbuf   + QKV1;
    __hip_bfloat16* WqkvT   = attnbuf + QKV1;
    __hip_bfloat16* WprojT  = WqkvT   + (size_t)C_ * 3 * C_;
    __hip_bfloat16* xbf     = WprojT  + (size_t)C_ * C_;
    float*          ropetab = (float*)(xbf + QKV1);

    xconv_kernel<<<(QKV1 / 4 + 255) / 256, 256, 0, stream>>>(x, xbf, (int)(QKV1 / 4));
    rope_tab_kernel<<<(NTOK * 32) / 256, 256, 0, stream>>>(keep_idx, orig_len, ropetab);

    dim3 tb(32, 8);
    transpose_conv_kernel<<<dim3(3 * C_ / 32, C_ / 32), tb, 0, stream>>>(Wqkv, WqkvT, C_, 3 * C_);
    transpose_conv_kernel<<<dim3(C_ / 32, C_ / 32), tb, 0, stream>>>(Wproj, WprojT, C_, C_);

    gemm_kernel<1><<<(8192 / 128) * (3072 / 128), 256, 0, stream>>>(
        xbf, WqkvT, bqkv, nullptr, qbuf, kbuf, vtbuf, ropetab, 8192, 3072, 1024);

    attn_kernel<<<(T_ / 128) * 64, 256, 0, stream>>>(qbuf, kbuf, vtbuf, attnbuf);

    gemm_kernel<0><<<(8192 / 128) * (1024 / 128), 256, 0, stream>>>(
        attnbuf, WprojT, bproj, out, nullptr, nullptr, nullptr, nullptr, 8192, 1024, 1024);
}

// Round 8
// 273.619 us; speedup vs baseline: 1.0366x; 1.0366x over previous
//
#include <hip/hip_runtime.h>
#include <hip/hip_bf16.h>
#include <math.h>

#define B_ 4
#define T_ 2048
#define C_ 1024
#define H_ 16
#define D_ 64

typedef __attribute__((ext_vector_type(8))) short bf16x8_t;   // 8 bf16 (4 VGPRs)
typedef __attribute__((ext_vector_type(4))) float f32x4_t;
typedef __attribute__((ext_vector_type(2))) unsigned int uiv2_t;

// q is pre-scaled by 0.125*log2(e) in the QKV epilogue, so scores arrive in
// base-2: p = exp2(s' - SHIFT2). |s|<=~8 => |s'|<=11.6; SHIFT2=32 keeps
// everything finite-positive; normalization cancels the shift exactly.
// The -SHIFT2 bias rides in as the C-operand of the first MFMA of each chain.
#define SHIFT2 32.0f

// async global->LDS DMA, 16B/lane; HW dest = wave-uniform lds base + lane*16
#define GLOAD_LDS16(gp, lp)                                                          \
    __builtin_amdgcn_global_load_lds(                                                \
        (const __attribute__((address_space(1))) void*)(gp),                         \
        (__attribute__((address_space(3))) void*)(lp), 16, 0, 0)

// compiler-only ordering (no instruction): per-wave LDS RAW relies on the
// in-order DS pipe (verified correct rounds 6-7)
#define WAVE_ORDER() __builtin_amdgcn_wave_barrier()

__device__ inline unsigned int pack2bf(float a, float b) {
    __hip_bfloat162 h = __float22bfloat162_rn(make_float2(a, b));  // v_cvt_pk_bf16_f32
    return *reinterpret_cast<unsigned int*>(&h);
}

// ---------------------------------------------------------------------------
// Fused prep: one launch replaces {xconv, rope_tab, Wqkv-transpose,
// Wproj-transpose} — 4 independent small kernels whose serial launch gaps
// cost more than their work. Block-uniform branch on blockIdx ranges.
//   [0, 8192)          xconv: x f32 -> bf16, 4 el/thread
//   [8192, 9216)       rope table: tab[token][0..31]=cos, [32..63]=sin
//   [9216, 12288)      Wqkv^T  (1024x3072 -> 3072x1024 bf16)
//   [12288, 13312)     Wproj^T (1024x1024 -> 1024x1024 bf16)
// ---------------------------------------------------------------------------
__global__ __launch_bounds__(256)
void prep_kernel(const float* __restrict__ x, __hip_bfloat16* __restrict__ xbf,
                 const int* __restrict__ keep, const int* __restrict__ orig,
                 float* __restrict__ tab,
                 const float* __restrict__ Wqkv, __hip_bfloat16* __restrict__ WqkvT,
                 const float* __restrict__ Wproj, __hip_bfloat16* __restrict__ WprojT) {
    __shared__ float s[32][33];
    const int bid = blockIdx.x;
    const int tid = threadIdx.x;

    if (bid < 8192) {
        // xconv: n4 = 8192*1024/4 = 2097152 = 8192 blocks * 256 exactly
        int i = bid * 256 + tid;
        float4 v = *(const float4*)(x + (size_t)i * 4);
        uint2 u;
        u.x = pack2bf(v.x, v.y);
        u.y = pack2bf(v.z, v.w);
        *(uint2*)(xbf + (size_t)i * 4) = u;
    } else if (bid < 9216) {
        // rope: 8192 tokens * 32 d = 262144 = 1024 blocks * 256
        int i = (bid - 8192) * 256 + tid;
        int tok = i >> 5, d = i & 31;
        float freq = 0.5f * exp2f((float)d * (6.321928094887362f / 31.0f));
        float ang  = 6.283185307179586f * ((float)keep[tok] / (float)(*orig)) * freq;
        tab[(size_t)tok * 64 + d]      = cosf(ang);
        tab[(size_t)tok * 64 + 32 + d] = sinf(ang);
    } else {
        const float* in;
        __hip_bfloat16* outp;
        int N, n0, k0, r;
        if (bid < 12288) {
            r = bid - 9216;                 // Wqkv: grid (96, 32)
            in = Wqkv; outp = WqkvT; N = 3 * C_;
            n0 = (r % 96) * 32; k0 = (r / 96) * 32;
        } else {
            r = bid - 12288;                // Wproj: grid (32, 32)
            in = Wproj; outp = WprojT; N = C_;
            n0 = (r % 32) * 32; k0 = (r / 32) * 32;
        }
        const int K = C_;
        const int tx = tid & 31;
        const int ty = tid >> 5;            // 0..7
#pragma unroll
        for (int yy = 0; yy < 32; yy += 8)
            s[ty + yy][tx] = in[(size_t)(k0 + ty + yy) * N + n0 + tx];
        __syncthreads();
#pragma unroll
        for (int yy = 0; yy < 32; yy += 8)
            outp[(size_t)(n0 + ty + yy) * K + k0 + tx] = __float2bfloat16(s[tx][ty + yy]);
    }
}

// ---------------------------------------------------------------------------
// GEMM 128x128 tile, BK=32, TRIPLE-BUFFERED global_load_lds staging with
// 2-deep counted-vmcnt pipeline (vmcnt(8): tiles t+1,t+2 in flight; the wait
// targets loads issued TWO iterations ago, covering ~900cy HBM latency).
// LDS XOR swizzle (T2, both-sides). NOTE: XCD-chunked blockIdx remap was
// A/B-tested round 6->7 and REGRESSED ~14 µs (the natural round-robin
// dispatch already keeps each XCD on one m-row sweeping n = A-panel-hot);
// reverted to identity mapping.
// MODE 0: f32 store. MODE 1: qkv epilogue; V transposed through LDS.
// ---------------------------------------------------------------------------
#define GTILE (128 * 32)

template <int MODE>
__global__ __launch_bounds__(256)
void gemm_kernel(const __hip_bfloat16* __restrict__ A,
                 const __hip_bfloat16* __restrict__ BT,
                 const float* __restrict__ bias,
                 float* __restrict__ out,
                 __hip_bfloat16* __restrict__ qbuf,
                 __hip_bfloat16* __restrict__ kbuf,
                 __hip_bfloat16* __restrict__ vtbuf,
                 const float* __restrict__ ropetab,
                 int M, int N, int K) {
    // GS[0..3*GTILE): A triple-buffer; GS[3*GTILE..6*GTILE): B triple-buffer.
    __shared__ __align__(16) __hip_bfloat16 GS[6 * GTILE];

    const int tid  = threadIdx.x;
    const int lane = tid & 63;
    const int wave = tid >> 6;
    const int wm   = wave >> 1;
    const int wn   = wave & 1;
    const int l15  = lane & 15;
    const int quad = lane >> 4;

    const int nT  = N >> 7;
    const int grp = blockIdx.x / (8 * nT);
    const int rem = blockIdx.x - grp * 8 * nT;
    const int m0  = (grp * 8 + (rem & 7)) * 128;
    const int n0  = (rem >> 3) * 128;

    f32x4_t acc[4][4];
#pragma unroll
    for (int i = 0; i < 4; i++)
#pragma unroll
        for (int j = 0; j < 4; j++) acc[i][j] = (f32x4_t)0.0f;

    const int lrow = lane >> 2;
    // pre-swizzled source chunk: LDS[row][p] holds global chunk p^((row>>2)&3)
    const int scol = ((lane & 3) ^ ((lane >> 4) & 3)) * 8;
    const __hip_bfloat16* gA  = A  + (size_t)(m0 + wave * 16 + lrow) * K + scol;
    const __hip_bfloat16* gA2 = gA + (size_t)64 * K;
    const __hip_bfloat16* gB  = BT + (size_t)(n0 + wave * 16 + lrow) * K + scol;
    const __hip_bfloat16* gB2 = gB + (size_t)64 * K;
    const int ldsW = wave * 16 * 32;   // this wave's stage destination (elements)

    const int NK = K >> 5;
    // prologue: stage K-tiles 0 and 1 into buffers 0 and 1
    GLOAD_LDS16(gA,  GS + ldsW);
    GLOAD_LDS16(gA2, GS + ldsW + 64 * 32);
    GLOAD_LDS16(gB,  GS + 3 * GTILE + ldsW);
    GLOAD_LDS16(gB2, GS + 3 * GTILE + ldsW + 64 * 32);
    if (NK > 1) {
        GLOAD_LDS16(gA  + 32, GS + GTILE + ldsW);
        GLOAD_LDS16(gA2 + 32, GS + GTILE + ldsW + 64 * 32);
        GLOAD_LDS16(gB  + 32, GS + 3 * GTILE + GTILE + ldsW);
        GLOAD_LDS16(gB2 + 32, GS + 3 * GTILE + GTILE + ldsW + 64 * 32);
    }

    int off = 0;
    for (int t = 0; t < NK; ++t) {
        if (t + 2 < NK) {
            int poff = off + 2 * GTILE;
            if (poff >= 3 * GTILE) poff -= 3 * GTILE;
            const int kk = (t + 2) << 5;
            GLOAD_LDS16(gA  + kk, GS + poff + ldsW);
            GLOAD_LDS16(gA2 + kk, GS + poff + ldsW + 64 * 32);
            GLOAD_LDS16(gB  + kk, GS + 3 * GTILE + poff + ldsW);
            GLOAD_LDS16(gB2 + kk, GS + 3 * GTILE + poff + ldsW + 64 * 32);
            // leave only tiles t+1,t+2 (8 newest) in flight; tile t drained
            asm volatile("s_waitcnt vmcnt(8)" ::: "memory");
        } else if (t + 1 < NK) {
            asm volatile("s_waitcnt vmcnt(4)" ::: "memory");
        } else {
            asm volatile("s_waitcnt vmcnt(0)" ::: "memory");
        }
        __builtin_amdgcn_s_barrier();            // all waves' cur-tile DMA done
        __builtin_amdgcn_sched_barrier(0);       // pin: no ds_read hoists above

        bf16x8_t af[4], bfv[4];
#pragma unroll
        for (int i = 0; i < 4; i++)
            af[i] = *(const bf16x8_t*)(GS + off + (wm * 64 + i * 16 + l15) * 32 +
                                       ((quad ^ (l15 >> 2)) * 8));
#pragma unroll
        for (int j = 0; j < 4; j++)
            bfv[j] = *(const bf16x8_t*)(GS + 3 * GTILE + off + (wn * 64 + j * 16 + l15) * 32 +
                                        ((quad ^ (l15 >> 2)) * 8));
#pragma unroll
        for (int i = 0; i < 4; i++)
#pragma unroll
            for (int j = 0; j < 4; j++)
                acc[i][j] = __builtin_amdgcn_mfma_f32_16x16x32_bf16(af[i], bfv[j], acc[i][j], 0, 0, 0);

        __builtin_amdgcn_sched_barrier(0);       // pin: no ds_read sinks below
        asm volatile("s_waitcnt lgkmcnt(0)" ::: "memory");  // my LDS reads done
        __builtin_amdgcn_s_barrier();            // WAR: buffer reusable

        off += GTILE;
        if (off == 3 * GTILE) off = 0;
    }

    float bv[4];
#pragma unroll
    for (int j = 0; j < 4; j++)
        bv[j] = bias[n0 + wn * 64 + j * 16 + l15];

    if (MODE == 0) {
#pragma unroll
        for (int i = 0; i < 4; i++)
#pragma unroll
            for (int r = 0; r < 4; r++) {
                int row = m0 + wm * 64 + i * 16 + quad * 4 + r;
#pragma unroll
                for (int j = 0; j < 4; j++) {
                    int col = n0 + wn * 64 + j * 16 + l15;
                    out[(size_t)row * N + col] = acc[i][j][r] + bv[j];
                }
            }
    } else {
        const int cb   = n0 + wn * 64;
        const int part = cb >> 10;           // 0=q 1=k 2=v  (uniform per block)
        if (part == 2) {
            // transpose 128t x 128d(2 heads) through LDS (free after K-loop),
            // then coalesced 16B stores. Region per wn: 64 d-rows x 136 (pad).
            const int hb = (n0 & 1023) >> 6;     // head at wn=0; wn adds +1
            __hip_bfloat16* myL = GS + wn * (64 * 136);
#pragma unroll
            for (int j = 0; j < 4; j++)
#pragma unroll
                for (int i = 0; i < 4; i++)
#pragma unroll
                    for (int r = 0; r < 4; r++) {
                        int rt = wm * 64 + i * 16 + quad * 4 + r;   // token in tile
                        int d  = j * 16 + l15;
                        myL[d * 136 + rt] = __float2bfloat16(acc[i][j][r] + bv[j]);
                    }
            __syncthreads();
            const int bb  = m0 >> 11;
            const int t0  = m0 & 2047;
            const int row = tid >> 1;            // 0..127 = wn2*64 + d
            const int wn2 = row >> 6;
            const int dd  = row & 63;
            const __hip_bfloat16* src = GS + wn2 * (64 * 136) + dd * 136;
            __hip_bfloat16* dstv = vtbuf +
                ((size_t)((bb * H_ + hb + wn2) * D_ + dd)) * T_ + t0;
#pragma unroll
            for (int s2 = 0; s2 < 8; s2++) {
                int ch = (tid & 1) * 8 + s2;
                *(bf16x8_t*)(dstv + ch * 8) = *(const bf16x8_t*)(src + ch * 8);
            }
        } else {
            const int h = (cb & 1023) >> 6;
            __hip_bfloat16* dst = (part == 0) ? qbuf : kbuf;
            // q: fold 1/sqrt(D) AND log2(e) so attention uses exp2 directly
            const float sc = (part == 0) ? 0.18033688011112042f : 1.0f;
#pragma unroll
            for (int i = 0; i < 4; i++) {
#pragma unroll
                for (int r = 0; r < 4; r++) {
                    int row = m0 + wm * 64 + i * 16 + quad * 4 + r;
                    int b = row >> 11;
                    int t = row & 2047;
                    const float* trow = ropetab + (size_t)row * 64;
                    size_t base = ((size_t)(b * H_ + h) * T_ + t) * D_;
#pragma unroll
                    for (int j = 0; j < 2; j++) {
                        int d = j * 16 + l15;
                        float cs = trow[d];
                        float sn = trow[32 + d];
                        float x1 = acc[i][j][r]     + bv[j];
                        float x2 = acc[i][j + 2][r] + bv[j + 2];
                        dst[base + d]      = __float2bfloat16(sc * (x1 * cs - x2 * sn));
                        dst[base + d + 32] = __float2bfloat16(sc * (x1 * sn + x2 * cs));
                    }
                }
            }
        }
    }
}

// ---------------------------------------------------------------------------
// Flash attention v8 (stable since round 3; v9 QBLK=64 regressed — occupancy
// 16->8 waves/CU lost more latency-hiding than amortization gained).
// QBLK=32/wave, 1024 blocks, 4 blocks/CU. Counted-vmcnt double-buffered
// K/V DMA, in-register P^T via permlane swaps, -SHIFT2 folded into MFMA
// C-in, setprio around MFMA clusters.
// ---------------------------------------------------------------------------
#define KVTILE (64 * 64)

__global__ __launch_bounds__(256, 4)
void attn_kernel(const __hip_bfloat16* __restrict__ q,
                 const __hip_bfloat16* __restrict__ k,
                 const __hip_bfloat16* __restrict__ vt,
                 __hip_bfloat16* __restrict__ attn_out) {
    // [0..1]*KVTILE: K double-buffer; [2..3]*KVTILE: V double-buffer (32 KB).
    // After the final barrier the front is reused as the per-wave epilogue
    // staging area (4 waves x 32 x 72 bf16 = 18 KB <= 32 KB).
    __shared__ __align__(16) __hip_bfloat16 SMEM[4 * KVTILE];

    const int tid  = threadIdx.x;
    const int lane = tid & 63;
    const int wave = tid >> 6;
    const int l15  = lane & 15;
    const int quad = lane >> 4;
    const int x7   = l15 & 7;

    const int bh = blockIdx.x & 63;          // XCD swizzle
    const int qt = blockIdx.x >> 6;          // 0..15
    const int b  = bh >> 4;
    const int h  = bh & 15;

    const size_t qkbase = (size_t)bh * T_ * D_;
    const size_t vbase  = (size_t)bh * D_ * T_;
    const int    qrow0  = qt * 128 + wave * 32;

    // DMA lane mapping: lane = drow*8 + dchunk; fetch global chunk dchunk^drow
    const int drow   = lane >> 3;        // 0..7
    const int gchunk = (lane & 7) ^ drow;

    const __hip_bfloat16* kg = k + qkbase;
    const __hip_bfloat16* vg = vt + vbase;

    // fragment-read swizzled chunk offsets (elements)
    const int c0 = ((quad)     ^ x7) * 8;
    const int c1 = ((4 + quad) ^ x7) * 8;

    // Q as B-fragment (n=qrow, k=d), direct global (once)
    bf16x8_t qa[2][2];
#pragma unroll
    for (int qf = 0; qf < 2; qf++)
#pragma unroll
        for (int kk = 0; kk < 2; kk++)
            qa[qf][kk] = *(const bf16x8_t*)(q + qkbase +
                          (size_t)(qrow0 + qf * 16 + l15) * D_ + kk * 32 + quad * 8);

    // all-ones A-fragment for MFMA row-sums
    bf16x8_t ones;
#pragma unroll
    for (int i = 0; i < 8; i++) ones[i] = (short)0x3F80;

    // loop-invariant C-operand: folds the -SHIFT2 softmax bias into the MFMA
    const f32x4_t mbias = (f32x4_t)(-SHIFT2);

    f32x4_t o[2][4];
#pragma unroll
    for (int qf = 0; qf < 2; qf++)
#pragma unroll
        for (int jd = 0; jd < 4; jd++) o[qf][jd] = (f32x4_t)0.0f;
    f32x4_t osum[2];
    osum[0] = (f32x4_t)0.0f;
    osum[1] = (f32x4_t)0.0f;

    // prologue: stage tile 0 into buffer 0 (iter-0 vmcnt+barrier syncs it)
#pragma unroll
    for (int i = 0; i < 2; i++) {
        int r = wave * 16 + i * 8;
        GLOAD_LDS16(kg + (size_t)(r + drow) * D_ + gchunk * 8, SMEM + r * 64);
        GLOAD_LDS16(vg + (size_t)(r + drow) * T_ + gchunk * 8, SMEM + 2 * KVTILE + r * 64);
    }

    for (int kt = 0; kt < T_ / 64; kt++) {
        const int curoff = (kt & 1) * KVTILE;
        const int nxtoff = curoff ^ KVTILE;
        // issue next tile's DMA FIRST; stays in flight across both barriers
        if (kt + 1 < T_ / 64) {
#pragma unroll
            for (int i = 0; i < 2; i++) {
                int r = wave * 16 + i * 8;
                GLOAD_LDS16(kg + (size_t)((kt + 1) * 64 + r + drow) * D_ + gchunk * 8,
                            SMEM + nxtoff + r * 64);
                GLOAD_LDS16(vg + (size_t)(r + drow) * T_ + (kt + 1) * 64 + gchunk * 8,
                            SMEM + 2 * KVTILE + nxtoff + r * 64);
            }
            // drain everything EXCEPT the 4 just-issued next-tile loads
            asm volatile("s_waitcnt vmcnt(4)" ::: "memory");
        } else {
            asm volatile("s_waitcnt vmcnt(0)" ::: "memory");
        }
        __builtin_amdgcn_s_barrier();            // all waves' cur-tile DMA done
        __builtin_amdgcn_sched_barrier(0);       // pin: no ds_read hoists above

        const __hip_bfloat16* KLc = SMEM + curoff;
        const __hip_bfloat16* VLc = SMEM + 2 * KVTILE + curoff;

        // K fragments (swizzled), then S^T = K.Q^T - SHIFT2 (bias via C-in)
        bf16x8_t kf[4][2];
#pragma unroll
        for (int jt = 0; jt < 4; jt++) {
            kf[jt][0] = *(const bf16x8_t*)(KLc + (jt * 16 + l15) * 64 + c0);
            kf[jt][1] = *(const bf16x8_t*)(KLc + (jt * 16 + l15) * 64 + c1);
        }

        f32x4_t sT[2][4];
        __builtin_amdgcn_s_setprio(1);
#pragma unroll
        for (int jt = 0; jt < 4; jt++)
#pragma unroll
            for (int qf = 0; qf < 2; qf++) {
                sT[qf][jt] = __builtin_amdgcn_mfma_f32_16x16x32_bf16(
                    kf[jt][0], qa[qf][0], mbias, 0, 0, 0);
                sT[qf][jt] = __builtin_amdgcn_mfma_f32_16x16x32_bf16(
                    kf[jt][1], qa[qf][1], sT[qf][jt], 0, 0, 0);
            }
        __builtin_amdgcn_s_setprio(0);

        // p = exp2(s'); pack to bf16 pairs, then build P^T B-fragments
        // entirely in registers via permlane swaps (no LDS round-trip).
        bf16x8_t pb[2][2];
#pragma unroll
        for (int qf = 0; qf < 2; qf++) {
            unsigned int w0[4], w1[4];
#pragma unroll
            for (int jt = 0; jt < 4; jt++) {
                float p0 = __builtin_amdgcn_exp2f(sT[qf][jt][0]);
                float p1 = __builtin_amdgcn_exp2f(sT[qf][jt][1]);
                float p2 = __builtin_amdgcn_exp2f(sT[qf][jt][2]);
                float p3 = __builtin_amdgcn_exp2f(sT[qf][jt][3]);
                w0[jt] = pack2bf(p0, p1);   // keys quad*4+0, +1
                w1[jt] = pack2bf(p2, p3);   // keys quad*4+2, +3
            }
#pragma unroll
            for (int kk = 0; kk < 2; kk++) {
                uiv2_t s0 = __builtin_amdgcn_permlane32_swap(w0[2 * kk], w0[2 * kk + 1], false, false);
                uiv2_t r0 = __builtin_amdgcn_permlane16_swap(s0[0], s0[1], false, false);
                uiv2_t s1 = __builtin_amdgcn_permlane32_swap(w1[2 * kk], w1[2 * kk + 1], false, false);
                uiv2_t r1 = __builtin_amdgcn_permlane16_swap(s1[0], s1[1], false, false);
                union { unsigned int u[4]; bf16x8_t v; } pu;
                pu.u[0] = r0[0];   // keys +0,1
                pu.u[1] = r1[0];   // keys +2,3
                pu.u[2] = r0[1];   // keys +4,5
                pu.u[3] = r1[1];   // keys +6,7
                pb[qf][kk] = pu.v;
            }
        }

        __builtin_amdgcn_s_setprio(1);
        // row-sums via ones-MFMA: every D row = sum_k P[n][k]
#pragma unroll
        for (int qf = 0; qf < 2; qf++) {
            osum[qf] = __builtin_amdgcn_mfma_f32_16x16x32_bf16(ones, pb[qf][0], osum[qf], 0, 0, 0);
            osum[qf] = __builtin_amdgcn_mfma_f32_16x16x32_bf16(ones, pb[qf][1], osum[qf], 0, 0, 0);
        }

        // o^T += V^T.P^T
#pragma unroll
        for (int jd = 0; jd < 4; jd++) {
            bf16x8_t vf0 = *(const bf16x8_t*)(VLc + (jd * 16 + l15) * 64 + c0);
            bf16x8_t vf1 = *(const bf16x8_t*)(VLc + (jd * 16 + l15) * 64 + c1);
#pragma unroll
            for (int qf = 0; qf < 2; qf++) {
                o[qf][jd] = __builtin_amdgcn_mfma_f32_16x16x32_bf16(vf0, pb[qf][0], o[qf][jd], 0, 0, 0);
                o[qf][jd] = __builtin_amdgcn_mfma_f32_16x16x32_bf16(vf1, pb[qf][1], o[qf][jd], 0, 0, 0);
            }
        }
        __builtin_amdgcn_s_setprio(0);

        __builtin_amdgcn_sched_barrier(0);       // pin: no ds_read sinks below
        asm volatile("s_waitcnt lgkmcnt(0)" ::: "memory");  // my LDS reads done
        __builtin_amdgcn_s_barrier();            // WAR: next iter may overwrite
    }

    // per-qrow inverse sums (all lanes/quads hold the value for their l15)
    float inv[2];
    inv[0] = 1.0f / osum[0][0];
    inv[1] = 1.0f / osum[1][0];

    // epilogue staging: reuse SMEM front (all K/V reads are behind the final
    // barrier above); per-wave private [32][72] bf16 region
    __hip_bfloat16* Pep = SMEM + wave * (32 * 72);

    WAVE_ORDER();
    // o^T -> LDS (packed b64), then coalesced 16B store
#pragma unroll
    for (int qf = 0; qf < 2; qf++) {
#pragma unroll
        for (int jd = 0; jd < 4; jd++) {
            uint2 pk;
            pk.x = pack2bf(o[qf][jd][0] * inv[qf], o[qf][jd][1] * inv[qf]);
            pk.y = pack2bf(o[qf][jd][2] * inv[qf], o[qf][jd][3] * inv[qf]);
            *(uint2*)(Pep + (qf * 16 + l15) * 72 + jd * 16 + quad * 4) = pk;
        }
    }
    WAVE_ORDER();

#pragma unroll
    for (int rnd = 0; rnd < 4; rnd++) {
        int row = rnd * 8 + (lane >> 3);
        int col = (lane & 7) * 8;
        bf16x8_t vrow = *(const bf16x8_t*)(Pep + row * 72 + col);
        int token = qt * 128 + wave * 32 + row;
        *(bf16x8_t*)(attn_out + ((size_t)(b * T_ + token)) * C_ + h * 64 + col) = vrow;
    }
}

// ---------------------------------------------------------------------------
extern "C" void kernel_launch(void* const* d_in, const int* in_sizes, int n_in,
                              void* d_out, int out_size, void* d_ws, size_t ws_size,
                              hipStream_t stream) {
    const float* x        = (const float*)d_in[0];
    const int*   keep_idx = (const int*)d_in[1];
    const int*   orig_len = (const int*)d_in[2];
    const float* Wqkv     = (const float*)d_in[3];
    const float* bqkv     = (const float*)d_in[4];
    const float* Wproj    = (const float*)d_in[5];
    const float* bproj    = (const float*)d_in[6];
    float*       out      = (float*)d_out;

    const size_t NTOK = (size_t)B_ * T_;
    const size_t QKV1 = NTOK * C_;

    __hip_bfloat16* qbuf    = (__hip_bfloat16*)d_ws;
    __hip_bfloat16* kbuf    = qbuf    + QKV1;
    __hip_bfloat16* vtbuf   = kbuf    + QKV1;
    __hip_bfloat16* attnbuf = vtbuf   + QKV1;
    __hip_bfloat16* WqkvT   = attnbuf + QKV1;
    __hip_bfloat16* WprojT  = WqkvT   + (size_t)C_ * 3 * C_;
    __hip_bfloat16* xbf     = WprojT  + (size_t)C_ * C_;
    float*          ropetab = (float*)(xbf + QKV1);

    // fused prep: xconv (8192) + rope (1024) + WqkvT (3072) + WprojT (1024)
    prep_kernel<<<13312, 256, 0, stream>>>(x, xbf, keep_idx, orig_len, ropetab,
                                           Wqkv, WqkvT, Wproj, WprojT);

    gemm_kernel<1><<<(8192 / 128) * (3072 / 128), 256, 0, stream>>>(
        xbf, WqkvT, bqkv, nullptr, qbuf, kbuf, vtbuf, ropetab, 8192, 3072, 1024);

    attn_kernel<<<(T_ / 128) * 64, 256, 0, stream>>>(qbuf, kbuf, vtbuf, attnbuf);

    gemm_kernel<0><<<(8192 / 128) * (1024 / 128), 256, 0, stream>>>(
        attnbuf, WprojT, bproj, out, nullptr, nullptr, nullptr, nullptr, 8192, 1024, 1024);
}

// Round 9
// 269.161 us; speedup vs baseline: 1.0538x; 1.0166x over previous
//
#include <hip/hip_runtime.h>
#include <hip/hip_bf16.h>
#include <math.h>

#define B_ 4
#define T_ 2048
#define C_ 1024
#define H_ 16
#define D_ 64

typedef __attribute__((ext_vector_type(8))) short bf16x8_t;   // 8 bf16 (4 VGPRs)
typedef __attribute__((ext_vector_type(4))) float f32x4_t;
typedef __attribute__((ext_vector_type(2))) unsigned int uiv2_t;

// q is pre-scaled by 0.125*log2(e) in the QKV epilogue, so scores arrive in
// base-2: p = exp2(s' - SHIFT2). |s|<=~8 => |s'|<=11.6; SHIFT2=32 keeps
// everything finite-positive; normalization cancels the shift exactly.
// The -SHIFT2 bias rides in as the C-operand of the first MFMA of each chain.
#define SHIFT2 32.0f

// async global->LDS DMA, 16B/lane; HW dest = wave-uniform lds base + lane*16
#define GLOAD_LDS16(gp, lp)                                                          \
    __builtin_amdgcn_global_load_lds(                                                \
        (const __attribute__((address_space(1))) void*)(gp),                         \
        (__attribute__((address_space(3))) void*)(lp), 16, 0, 0)

// compiler-only ordering (no instruction): per-wave LDS RAW relies on the
// in-order DS pipe (verified correct rounds 6-7)
#define WAVE_ORDER() __builtin_amdgcn_wave_barrier()

__device__ inline unsigned int pack2bf(float a, float b) {
    __hip_bfloat162 h = __float22bfloat162_rn(make_float2(a, b));  // v_cvt_pk_bf16_f32
    return *reinterpret_cast<unsigned int*>(&h);
}

// ---------------------------------------------------------------------------
// Fused prep: one launch replaces {xconv, rope_tab, Wqkv-transpose,
// Wproj-transpose}. Block-uniform branch on blockIdx ranges.
//   [0, 8192)          xconv: x f32 -> bf16, 4 el/thread
//   [8192, 9216)       rope table: tab[token][0..31]=cos, [32..63]=sin
//   [9216, 12288)      Wqkv^T  (1024x3072 -> 3072x1024 bf16)
//   [12288, 13312)     Wproj^T (1024x1024 -> 1024x1024 bf16)
// ---------------------------------------------------------------------------
__global__ __launch_bounds__(256)
void prep_kernel(const float* __restrict__ x, __hip_bfloat16* __restrict__ xbf,
                 const int* __restrict__ keep, const int* __restrict__ orig,
                 float* __restrict__ tab,
                 const float* __restrict__ Wqkv, __hip_bfloat16* __restrict__ WqkvT,
                 const float* __restrict__ Wproj, __hip_bfloat16* __restrict__ WprojT) {
    __shared__ float s[32][33];
    const int bid = blockIdx.x;
    const int tid = threadIdx.x;

    if (bid < 8192) {
        int i = bid * 256 + tid;
        float4 v = *(const float4*)(x + (size_t)i * 4);
        uint2 u;
        u.x = pack2bf(v.x, v.y);
        u.y = pack2bf(v.z, v.w);
        *(uint2*)(xbf + (size_t)i * 4) = u;
    } else if (bid < 9216) {
        int i = (bid - 8192) * 256 + tid;
        int tok = i >> 5, d = i & 31;
        float freq = 0.5f * exp2f((float)d * (6.321928094887362f / 31.0f));
        float ang  = 6.283185307179586f * ((float)keep[tok] / (float)(*orig)) * freq;
        tab[(size_t)tok * 64 + d]      = cosf(ang);
        tab[(size_t)tok * 64 + 32 + d] = sinf(ang);
    } else {
        const float* in;
        __hip_bfloat16* outp;
        int N, n0, k0, r;
        if (bid < 12288) {
            r = bid - 9216;                 // Wqkv: grid (96, 32)
            in = Wqkv; outp = WqkvT; N = 3 * C_;
            n0 = (r % 96) * 32; k0 = (r / 96) * 32;
        } else {
            r = bid - 12288;                // Wproj: grid (32, 32)
            in = Wproj; outp = WprojT; N = C_;
            n0 = (r % 32) * 32; k0 = (r / 32) * 32;
        }
        const int K = C_;
        const int tx = tid & 31;
        const int ty = tid >> 5;            // 0..7
#pragma unroll
        for (int yy = 0; yy < 32; yy += 8)
            s[ty + yy][tx] = in[(size_t)(k0 + ty + yy) * N + n0 + tx];
        __syncthreads();
#pragma unroll
        for (int yy = 0; yy < 32; yy += 8)
            outp[(size_t)(n0 + ty + yy) * K + k0 + tx] = __float2bfloat16(s[tx][ty + yy]);
    }
}

// ---------------------------------------------------------------------------
// GEMM 256x128 tile, 8 waves (512 thr), BK=32, DOUBLE-BUFFERED
// global_load_lds staging with counted vmcnt(3) (3 loads/wave/tile: A x2,
// B x1 — B-panel staging per FLOP halves vs the 128x128 kernel, A HBM
// fetch per FLOP halves, barrier count per FLOP halves). Per-wave work is
// the identical proven 64x64 acc[4][4] 16-MFMA structure (wm=wave>>1 0..3,
// wn=wave&1). Occupancy: 48KB LDS, ~110 VGPR -> 2 blocks x 8 waves =
// 16 waves/CU (was 12). LDS XOR swizzle (T2, both-sides) as before.
// MODE 0: f32 store. MODE 1: qkv epilogue; V transposed through LDS in
// two 128-token passes ([128][136] region fits the 48KB buffer).
// ---------------------------------------------------------------------------
#define ATILE (256 * 32)
#define BTILE (128 * 32)

template <int MODE>
__global__ __launch_bounds__(512)
void gemm_kernel(const __hip_bfloat16* __restrict__ A,
                 const __hip_bfloat16* __restrict__ BT,
                 const float* __restrict__ bias,
                 float* __restrict__ out,
                 __hip_bfloat16* __restrict__ qbuf,
                 __hip_bfloat16* __restrict__ kbuf,
                 __hip_bfloat16* __restrict__ vtbuf,
                 const float* __restrict__ ropetab,
                 int M, int N, int K) {
    // [0..2*ATILE): A double-buffer; [2*ATILE..): B double-buffer. 48 KB.
    __shared__ __align__(16) __hip_bfloat16 GS[2 * ATILE + 2 * BTILE];

    const int tid  = threadIdx.x;
    const int lane = tid & 63;
    const int wave = tid >> 6;          // 0..7
    const int wm   = wave >> 1;         // 0..3 (m quadrant)
    const int wn   = wave & 1;          // 0..1 (n half)
    const int l15  = lane & 15;
    const int quad = lane >> 4;

    const int nT  = N >> 7;
    const int grp = blockIdx.x / (8 * nT);
    const int rem = blockIdx.x - grp * 8 * nT;
    const int m0  = (grp * 8 + (rem & 7)) * 256;
    const int n0  = (rem >> 3) * 128;

    f32x4_t acc[4][4];
#pragma unroll
    for (int i = 0; i < 4; i++)
#pragma unroll
        for (int j = 0; j < 4; j++) acc[i][j] = (f32x4_t)0.0f;

    const int lrow = lane >> 2;
    // pre-swizzled source chunk: LDS[row][p] holds global chunk p^((row>>2)&3)
    const int scol = ((lane & 3) ^ ((lane >> 4) & 3)) * 8;
    const __hip_bfloat16* gA  = A  + (size_t)(m0 + wave * 32 + lrow) * K + scol;
    const __hip_bfloat16* gA2 = gA + (size_t)16 * K;
    const __hip_bfloat16* gB  = BT + (size_t)(n0 + wave * 16 + lrow) * K + scol;
    const int ldsA = wave * 32 * 32;   // this wave's A rows (elements)
    const int ldsB = wave * 16 * 32;   // this wave's B rows (elements)

    const int NK = K >> 5;
    // prologue: stage K-tile 0 into buffer 0
    GLOAD_LDS16(gA,  GS + ldsA);
    GLOAD_LDS16(gA2, GS + ldsA + 16 * 32);
    GLOAD_LDS16(gB,  GS + 2 * ATILE + ldsB);

    for (int t = 0; t < NK; ++t) {
        const int Ab = (t & 1) * ATILE;
        const int Bb = 2 * ATILE + (t & 1) * BTILE;
        if (t + 1 < NK) {
            const int An = (~t & 1) * ATILE;
            const int Bn = 2 * ATILE + (~t & 1) * BTILE;
            const int kk = (t + 1) << 5;
            GLOAD_LDS16(gA  + kk, GS + An + ldsA);
            GLOAD_LDS16(gA2 + kk, GS + An + ldsA + 16 * 32);
            GLOAD_LDS16(gB  + kk, GS + Bn + ldsB);
            // drain everything EXCEPT the 3 just-issued next-tile loads
            asm volatile("s_waitcnt vmcnt(3)" ::: "memory");
        } else {
            asm volatile("s_waitcnt vmcnt(0)" ::: "memory");
        }
        __builtin_amdgcn_s_barrier();            // all waves' cur-tile DMA done
        __builtin_amdgcn_sched_barrier(0);       // pin: no ds_read hoists above

        bf16x8_t af[4], bfv[4];
#pragma unroll
        for (int i = 0; i < 4; i++)
            af[i] = *(const bf16x8_t*)(GS + Ab + (wm * 64 + i * 16 + l15) * 32 +
                                       ((quad ^ (l15 >> 2)) * 8));
#pragma unroll
        for (int j = 0; j < 4; j++)
            bfv[j] = *(const bf16x8_t*)(GS + Bb + (wn * 64 + j * 16 + l15) * 32 +
                                        ((quad ^ (l15 >> 2)) * 8));
#pragma unroll
        for (int i = 0; i < 4; i++)
#pragma unroll
            for (int j = 0; j < 4; j++)
                acc[i][j] = __builtin_amdgcn_mfma_f32_16x16x32_bf16(af[i], bfv[j], acc[i][j], 0, 0, 0);

        __builtin_amdgcn_sched_barrier(0);       // pin: no ds_read sinks below
        asm volatile("s_waitcnt lgkmcnt(0)" ::: "memory");  // my LDS reads done
        __builtin_amdgcn_s_barrier();            // WAR: buffer reusable
    }

    float bv[4];
#pragma unroll
    for (int j = 0; j < 4; j++)
        bv[j] = bias[n0 + wn * 64 + j * 16 + l15];

    if (MODE == 0) {
#pragma unroll
        for (int i = 0; i < 4; i++)
#pragma unroll
            for (int r = 0; r < 4; r++) {
                int row = m0 + wm * 64 + i * 16 + quad * 4 + r;
#pragma unroll
                for (int j = 0; j < 4; j++) {
                    int col = n0 + wn * 64 + j * 16 + l15;
                    out[(size_t)row * N + col] = acc[i][j][r] + bv[j];
                }
            }
    } else {
        const int cb   = n0 + wn * 64;
        const int part = cb >> 10;           // 0=q 1=k 2=v  (uniform per block:
                                             // n0 is a multiple of 128, so no
                                             // block straddles the 1024/2048
                                             // boundaries)
        if (part == 2) {
            // V: transpose 256 tokens x 128 d (2 heads) through LDS in two
            // 128-token passes; region L=[128 d][136] (pad) fits 48KB GS.
            const int hb = (n0 & 1023) >> 6;     // even head base
            const int bb = m0 >> 11;
            const int t0 = m0 & 2047;            // multiple of 256
            __hip_bfloat16* L = GS;
#pragma unroll
            for (int p = 0; p < 2; ++p) {
                if ((wm >> 1) == p) {            // waves owning this 128-token half
#pragma unroll
                    for (int j = 0; j < 4; j++) {
                        int d = wn * 64 + j * 16 + l15;
#pragma unroll
                        for (int i = 0; i < 4; i++) {
                            int rtb = (wm & 1) * 64 + i * 16 + quad * 4;
                            uint2 pk;
                            pk.x = pack2bf(acc[i][j][0] + bv[j], acc[i][j][1] + bv[j]);
                            pk.y = pack2bf(acc[i][j][2] + bv[j], acc[i][j][3] + bv[j]);
                            *(uint2*)(L + d * 136 + rtb) = pk;
                        }
                    }
                }
                __syncthreads();
                {
                    int row = tid >> 2;          // 0..127 = (head-off<<6)|dd
                    int hb2 = hb + (row >> 6);
                    int dd  = row & 63;
                    const __hip_bfloat16* src = L + row * 136;
                    __hip_bfloat16* dstv = vtbuf +
                        ((size_t)((bb * H_ + hb2) * D_ + dd)) * T_ + t0 + p * 128;
#pragma unroll
                    for (int s2 = 0; s2 < 4; s2++) {
                        int ch = (tid & 3) + s2 * 4;
                        *(bf16x8_t*)(dstv + ch * 8) = *(const bf16x8_t*)(src + ch * 8);
                    }
                }
                if (p == 0) __syncthreads();     // WAR before pass-1 L writes
            }
        } else {
            const int h = (cb & 1023) >> 6;
            __hip_bfloat16* dst = (part == 0) ? qbuf : kbuf;
            // q: fold 1/sqrt(D) AND log2(e) so attention uses exp2 directly
            const float sc = (part == 0) ? 0.18033688011112042f : 1.0f;
#pragma unroll
            for (int i = 0; i < 4; i++) {
#pragma unroll
                for (int r = 0; r < 4; r++) {
                    int row = m0 + wm * 64 + i * 16 + quad * 4 + r;
                    int b = row >> 11;
                    int t = row & 2047;
                    const float* trow = ropetab + (size_t)row * 64;
                    size_t base = ((size_t)(b * H_ + h) * T_ + t) * D_;
#pragma unroll
                    for (int j = 0; j < 2; j++) {
                        int d = j * 16 + l15;
                        float cs = trow[d];
                        float sn = trow[32 + d];
                        float x1 = acc[i][j][r]     + bv[j];
                        float x2 = acc[i][j + 2][r] + bv[j + 2];
                        dst[base + d]      = __float2bfloat16(sc * (x1 * cs - x2 * sn));
                        dst[base + d + 32] = __float2bfloat16(sc * (x1 * sn + x2 * cs));
                    }
                }
            }
        }
    }
}

// ---------------------------------------------------------------------------
// Flash attention v8 (stable since round 3; v9 QBLK=64 regressed — occupancy
// 16->8 waves/CU lost more latency-hiding than amortization gained).
// QBLK=32/wave, 1024 blocks, 4 blocks/CU. Counted-vmcnt double-buffered
// K/V DMA, in-register P^T via permlane swaps, -SHIFT2 folded into MFMA
// C-in, setprio around MFMA clusters.
// ---------------------------------------------------------------------------
#define KVTILE (64 * 64)

__global__ __launch_bounds__(256, 4)
void attn_kernel(const __hip_bfloat16* __restrict__ q,
                 const __hip_bfloat16* __restrict__ k,
                 const __hip_bfloat16* __restrict__ vt,
                 __hip_bfloat16* __restrict__ attn_out) {
    // [0..1]*KVTILE: K double-buffer; [2..3]*KVTILE: V double-buffer (32 KB).
    // After the final barrier the front is reused as the per-wave epilogue
    // staging area (4 waves x 32 x 72 bf16 = 18 KB <= 32 KB).
    __shared__ __align__(16) __hip_bfloat16 SMEM[4 * KVTILE];

    const int tid  = threadIdx.x;
    const int lane = tid & 63;
    const int wave = tid >> 6;
    const int l15  = lane & 15;
    const int quad = lane >> 4;
    const int x7   = l15 & 7;

    const int bh = blockIdx.x & 63;          // XCD swizzle
    const int qt = blockIdx.x >> 6;          // 0..15
    const int b  = bh >> 4;
    const int h  = bh & 15;

    const size_t qkbase = (size_t)bh * T_ * D_;
    const size_t vbase  = (size_t)bh * D_ * T_;
    const int    qrow0  = qt * 128 + wave * 32;

    // DMA lane mapping: lane = drow*8 + dchunk; fetch global chunk dchunk^drow
    const int drow   = lane >> 3;        // 0..7
    const int gchunk = (lane & 7) ^ drow;

    const __hip_bfloat16* kg = k + qkbase;
    const __hip_bfloat16* vg = vt + vbase;

    // fragment-read swizzled chunk offsets (elements)
    const int c0 = ((quad)     ^ x7) * 8;
    const int c1 = ((4 + quad) ^ x7) * 8;

    // Q as B-fragment (n=qrow, k=d), direct global (once)
    bf16x8_t qa[2][2];
#pragma unroll
    for (int qf = 0; qf < 2; qf++)
#pragma unroll
        for (int kk = 0; kk < 2; kk++)
            qa[qf][kk] = *(const bf16x8_t*)(q + qkbase +
                          (size_t)(qrow0 + qf * 16 + l15) * D_ + kk * 32 + quad * 8);

    // all-ones A-fragment for MFMA row-sums
    bf16x8_t ones;
#pragma unroll
    for (int i = 0; i < 8; i++) ones[i] = (short)0x3F80;

    // loop-invariant C-operand: folds the -SHIFT2 softmax bias into the MFMA
    const f32x4_t mbias = (f32x4_t)(-SHIFT2);

    f32x4_t o[2][4];
#pragma unroll
    for (int qf = 0; qf < 2; qf++)
#pragma unroll
        for (int jd = 0; jd < 4; jd++) o[qf][jd] = (f32x4_t)0.0f;
    f32x4_t osum[2];
    osum[0] = (f32x4_t)0.0f;
    osum[1] = (f32x4_t)0.0f;

    // prologue: stage tile 0 into buffer 0 (iter-0 vmcnt+barrier syncs it)
#pragma unroll
    for (int i = 0; i < 2; i++) {
        int r = wave * 16 + i * 8;
        GLOAD_LDS16(kg + (size_t)(r + drow) * D_ + gchunk * 8, SMEM + r * 64);
        GLOAD_LDS16(vg + (size_t)(r + drow) * T_ + gchunk * 8, SMEM + 2 * KVTILE + r * 64);
    }

    for (int kt = 0; kt < T_ / 64; kt++) {
        const int curoff = (kt & 1) * KVTILE;
        const int nxtoff = curoff ^ KVTILE;
        // issue next tile's DMA FIRST; stays in flight across both barriers
        if (kt + 1 < T_ / 64) {
#pragma unroll
            for (int i = 0; i < 2; i++) {
                int r = wave * 16 + i * 8;
                GLOAD_LDS16(kg + (size_t)((kt + 1) * 64 + r + drow) * D_ + gchunk * 8,
                            SMEM + nxtoff + r * 64);
                GLOAD_LDS16(vg + (size_t)(r + drow) * T_ + (kt + 1) * 64 + gchunk * 8,
                            SMEM + 2 * KVTILE + nxtoff + r * 64);
            }
            // drain everything EXCEPT the 4 just-issued next-tile loads
            asm volatile("s_waitcnt vmcnt(4)" ::: "memory");
        } else {
            asm volatile("s_waitcnt vmcnt(0)" ::: "memory");
        }
        __builtin_amdgcn_s_barrier();            // all waves' cur-tile DMA done
        __builtin_amdgcn_sched_barrier(0);       // pin: no ds_read hoists above

        const __hip_bfloat16* KLc = SMEM + curoff;
        const __hip_bfloat16* VLc = SMEM + 2 * KVTILE + curoff;

        // K fragments (swizzled), then S^T = K.Q^T - SHIFT2 (bias via C-in)
        bf16x8_t kf[4][2];
#pragma unroll
        for (int jt = 0; jt < 4; jt++) {
            kf[jt][0] = *(const bf16x8_t*)(KLc + (jt * 16 + l15) * 64 + c0);
            kf[jt][1] = *(const bf16x8_t*)(KLc + (jt * 16 + l15) * 64 + c1);
        }

        f32x4_t sT[2][4];
        __builtin_amdgcn_s_setprio(1);
#pragma unroll
        for (int jt = 0; jt < 4; jt++)
#pragma unroll
            for (int qf = 0; qf < 2; qf++) {
                sT[qf][jt] = __builtin_amdgcn_mfma_f32_16x16x32_bf16(
                    kf[jt][0], qa[qf][0], mbias, 0, 0, 0);
                sT[qf][jt] = __builtin_amdgcn_mfma_f32_16x16x32_bf16(
                    kf[jt][1], qa[qf][1], sT[qf][jt], 0, 0, 0);
            }
        __builtin_amdgcn_s_setprio(0);

        // p = exp2(s'); pack to bf16 pairs, then build P^T B-fragments
        // entirely in registers via permlane swaps (no LDS round-trip).
        bf16x8_t pb[2][2];
#pragma unroll
        for (int qf = 0; qf < 2; qf++) {
            unsigned int w0[4], w1[4];
#pragma unroll
            for (int jt = 0; jt < 4; jt++) {
                float p0 = __builtin_amdgcn_exp2f(sT[qf][jt][0]);
                float p1 = __builtin_amdgcn_exp2f(sT[qf][jt][1]);
                float p2 = __builtin_amdgcn_exp2f(sT[qf][jt][2]);
                float p3 = __builtin_amdgcn_exp2f(sT[qf][jt][3]);
                w0[jt] = pack2bf(p0, p1);   // keys quad*4+0, +1
                w1[jt] = pack2bf(p2, p3);   // keys quad*4+2, +3
            }
#pragma unroll
            for (int kk = 0; kk < 2; kk++) {
                uiv2_t s0 = __builtin_amdgcn_permlane32_swap(w0[2 * kk], w0[2 * kk + 1], false, false);
                uiv2_t r0 = __builtin_amdgcn_permlane16_swap(s0[0], s0[1], false, false);
                uiv2_t s1 = __builtin_amdgcn_permlane32_swap(w1[2 * kk], w1[2 * kk + 1], false, false);
                uiv2_t r1 = __builtin_amdgcn_permlane16_swap(s1[0], s1[1], false, false);
                union { unsigned int u[4]; bf16x8_t v; } pu;
                pu.u[0] = r0[0];   // keys +0,1
                pu.u[1] = r1[0];   // keys +2,3
                pu.u[2] = r0[1];   // keys +4,5
                pu.u[3] = r1[1];   // keys +6,7
                pb[qf][kk] = pu.v;
            }
        }

        __builtin_amdgcn_s_setprio(1);
        // row-sums via ones-MFMA: every D row = sum_k P[n][k]
#pragma unroll
        for (int qf = 0; qf < 2; qf++) {
            osum[qf] = __builtin_amdgcn_mfma_f32_16x16x32_bf16(ones, pb[qf][0], osum[qf], 0, 0, 0);
            osum[qf] = __builtin_amdgcn_mfma_f32_16x16x32_bf16(ones, pb[qf][1], osum[qf], 0, 0, 0);
        }

        // o^T += V^T.P^T
#pragma unroll
        for (int jd = 0; jd < 4; jd++) {
            bf16x8_t vf0 = *(const bf16x8_t*)(VLc + (jd * 16 + l15) * 64 + c0);
            bf16x8_t vf1 = *(const bf16x8_t*)(VLc + (jd * 16 + l15) * 64 + c1);
#pragma unroll
            for (int qf = 0; qf < 2; qf++) {
                o[qf][jd] = __builtin_amdgcn_mfma_f32_16x16x32_bf16(vf0, pb[qf][0], o[qf][jd], 0, 0, 0);
                o[qf][jd] = __builtin_amdgcn_mfma_f32_16x16x32_bf16(vf1, pb[qf][1], o[qf][jd], 0, 0, 0);
            }
        }
        __builtin_amdgcn_s_setprio(0);

        __builtin_amdgcn_sched_barrier(0);       // pin: no ds_read sinks below
        asm volatile("s_waitcnt lgkmcnt(0)" ::: "memory");  // my LDS reads done
        __builtin_amdgcn_s_barrier();            // WAR: next iter may overwrite
    }

    // per-qrow inverse sums (all lanes/quads hold the value for their l15)
    float inv[2];
    inv[0] = 1.0f / osum[0][0];
    inv[1] = 1.0f / osum[1][0];

    // epilogue staging: reuse SMEM front (all K/V reads are behind the final
    // barrier above); per-wave private [32][72] bf16 region
    __hip_bfloat16* Pep = SMEM + wave * (32 * 72);

    WAVE_ORDER();
    // o^T -> LDS (packed b64), then coalesced 16B store
#pragma unroll
    for (int qf = 0; qf < 2; qf++) {
#pragma unroll
        for (int jd = 0; jd < 4; jd++) {
            uint2 pk;
            pk.x = pack2bf(o[qf][jd][0] * inv[qf], o[qf][jd][1] * inv[qf]);
            pk.y = pack2bf(o[qf][jd][2] * inv[qf], o[qf][jd][3] * inv[qf]);
            *(uint2*)(Pep + (qf * 16 + l15) * 72 + jd * 16 + quad * 4) = pk;
        }
    }
    WAVE_ORDER();

#pragma unroll
    for (int rnd = 0; rnd < 4; rnd++) {
        int row = rnd * 8 + (lane >> 3);
        int col = (lane & 7) * 8;
        bf16x8_t vrow = *(const bf16x8_t*)(Pep + row * 72 + col);
        int token = qt * 128 + wave * 32 + row;
        *(bf16x8_t*)(attn_out + ((size_t)(b * T_ + token)) * C_ + h * 64 + col) = vrow;
    }
}

// ---------------------------------------------------------------------------
extern "C" void kernel_launch(void* const* d_in, const int* in_sizes, int n_in,
                              void* d_out, int out_size, void* d_ws, size_t ws_size,
                              hipStream_t stream) {
    const float* x        = (const float*)d_in[0];
    const int*   keep_idx = (const int*)d_in[1];
    const int*   orig_len = (const int*)d_in[2];
    const float* Wqkv     = (const float*)d_in[3];
    const float* bqkv     = (const float*)d_in[4];
    const float* Wproj    = (const float*)d_in[5];
    const float* bproj    = (const float*)d_in[6];
    float*       out      = (float*)d_out;

    const size_t NTOK = (size_t)B_ * T_;
    const size_t QKV1 = NTOK * C_;

    __hip_bfloat16* qbuf    = (__hip_bfloat16*)d_ws;
    __hip_bfloat16* kbuf    = qbuf    + QKV1;
    __hip_bfloat16* vtbuf   = kbuf    + QKV1;
    __hip_bfloat16* attnbuf = vtbuf   + QKV1;
    __hip_bfloat16* WqkvT   = attnbuf + QKV1;
    __hip_bfloat16* WprojT  = WqkvT   + (size_t)C_ * 3 * C_;
    __hip_bfloat16* xbf     = WprojT  + (size_t)C_ * C_;
    float*          ropetab = (float*)(xbf + QKV1);

    // fused prep: xconv (8192) + rope (1024) + WqkvT (3072) + WprojT (1024)
    prep_kernel<<<13312, 256, 0, stream>>>(x, xbf, keep_idx, orig_len, ropetab,
                                           Wqkv, WqkvT, Wproj, WprojT);

    gemm_kernel<1><<<(8192 / 256) * (3072 / 128), 512, 0, stream>>>(
        xbf, WqkvT, bqkv, nullptr, qbuf, kbuf, vtbuf, ropetab, 8192, 3072, 1024);

    attn_kernel<<<(T_ / 128) * 64, 256, 0, stream>>>(qbuf, kbuf, vtbuf, attnbuf);

    gemm_kernel<0><<<(8192 / 256) * (1024 / 128), 512, 0, stream>>>(
        attnbuf, WprojT, bproj, out, nullptr, nullptr, nullptr, nullptr, 8192, 1024, 1024);
}

// Round 10
// 262.072 us; speedup vs baseline: 1.0823x; 1.0270x over previous
//
#include <hip/hip_runtime.h>
#include <hip/hip_bf16.h>
#include <math.h>

#define B_ 4
#define T_ 2048
#define C_ 1024
#define H_ 16
#define D_ 64

typedef __attribute__((ext_vector_type(8))) short bf16x8_t;   // 8 bf16 (4 VGPRs)
typedef __attribute__((ext_vector_type(4))) float f32x4_t;
typedef __attribute__((ext_vector_type(2))) unsigned int uiv2_t;

// q is pre-scaled by 0.125*log2(e) in the QKV epilogue, so scores arrive in
// base-2: p = exp2(s' - SHIFT2). |s|<=~8 => |s'|<=11.6; SHIFT2=32 keeps
// everything finite-positive; normalization cancels the shift exactly.
// The -SHIFT2 bias rides in as the C-operand of the first MFMA of each chain.
#define SHIFT2 32.0f

// async global->LDS DMA, 16B/lane; HW dest = wave-uniform lds base + lane*16
#define GLOAD_LDS16(gp, lp)                                                          \
    __builtin_amdgcn_global_load_lds(                                                \
        (const __attribute__((address_space(1))) void*)(gp),                         \
        (__attribute__((address_space(3))) void*)(lp), 16, 0, 0)

// compiler-only ordering (no instruction): per-wave LDS RAW relies on the
// in-order DS pipe (verified correct rounds 6-7)
#define WAVE_ORDER() __builtin_amdgcn_wave_barrier()

__device__ inline unsigned int pack2bf(float a, float b) {
    __hip_bfloat162 h = __float22bfloat162_rn(make_float2(a, b));  // v_cvt_pk_bf16_f32
    return *reinterpret_cast<unsigned int*>(&h);
}

// ---------------------------------------------------------------------------
// Fused prep: one launch replaces {xconv, rope_tab, Wqkv-transpose,
// Wproj-transpose}. Block-uniform branch on blockIdx ranges.
//   [0, 8192)          xconv: x f32 -> bf16, 4 el/thread
//   [8192, 9216)       rope table: tab[token][0..31]=cos, [32..63]=sin
//   [9216, 12288)      Wqkv^T  (1024x3072 -> 3072x1024 bf16)
//   [12288, 13312)     Wproj^T (1024x1024 -> 1024x1024 bf16)
// ---------------------------------------------------------------------------
__global__ __launch_bounds__(256)
void prep_kernel(const float* __restrict__ x, __hip_bfloat16* __restrict__ xbf,
                 const int* __restrict__ keep, const int* __restrict__ orig,
                 float* __restrict__ tab,
                 const float* __restrict__ Wqkv, __hip_bfloat16* __restrict__ WqkvT,
                 const float* __restrict__ Wproj, __hip_bfloat16* __restrict__ WprojT) {
    __shared__ float s[32][33];
    const int bid = blockIdx.x;
    const int tid = threadIdx.x;

    if (bid < 8192) {
        int i = bid * 256 + tid;
        float4 v = *(const float4*)(x + (size_t)i * 4);
        uint2 u;
        u.x = pack2bf(v.x, v.y);
        u.y = pack2bf(v.z, v.w);
        *(uint2*)(xbf + (size_t)i * 4) = u;
    } else if (bid < 9216) {
        int i = (bid - 8192) * 256 + tid;
        int tok = i >> 5, d = i & 31;
        float freq = 0.5f * exp2f((float)d * (6.321928094887362f / 31.0f));
        float ang  = 6.283185307179586f * ((float)keep[tok] / (float)(*orig)) * freq;
        tab[(size_t)tok * 64 + d]      = cosf(ang);
        tab[(size_t)tok * 64 + 32 + d] = sinf(ang);
    } else {
        const float* in;
        __hip_bfloat16* outp;
        int N, n0, k0, r;
        if (bid < 12288) {
            r = bid - 9216;                 // Wqkv: grid (96, 32)
            in = Wqkv; outp = WqkvT; N = 3 * C_;
            n0 = (r % 96) * 32; k0 = (r / 96) * 32;
        } else {
            r = bid - 12288;                // Wproj: grid (32, 32)
            in = Wproj; outp = WprojT; N = C_;
            n0 = (r % 32) * 32; k0 = (r / 32) * 32;
        }
        const int K = C_;
        const int tx = tid & 31;
        const int ty = tid >> 5;            // 0..7
#pragma unroll
        for (int yy = 0; yy < 32; yy += 8)
            s[ty + yy][tx] = in[(size_t)(k0 + ty + yy) * N + n0 + tx];
        __syncthreads();
#pragma unroll
        for (int yy = 0; yy < 32; yy += 8)
            outp[(size_t)(n0 + ty + yy) * K + k0 + tx] = __float2bfloat16(s[tx][ty + yy]);
    }
}

// ---------------------------------------------------------------------------
// GEMM 256x128 tile, 8 waves (512 thr), BK=32, TRIPLE-BUFFERED staging with
// ONE barrier per K-step:
//   vmcnt(3|0)  [tile t landed; tile t+1's 3 loads may stay in flight]
//   barrier     [all waves' iter t-1 reads are in registers]
//   issue tile t+2 -> buf (t+2)%3   [that buffer was last read at iter t-1]
//   compute buf t%3                 [no tail barrier, no lgkmcnt drain]
// WAR safety: the DMA target was read strictly before the barrier; a wave's
// ds_read data is consumed (regs) before it can reach the barrier. DMA-to-
// wait window = 2 full iterations (~2x the previous latency cover).
// LDS 72 KB -> still 2 blocks/CU (144 <= 160 KiB): occupancy unchanged,
// barriers halved. LDS XOR swizzle (T2, both-sides) as before.
// MODE 0: f32 store. MODE 1: qkv epilogue; V transposed through LDS in
// two 128-token passes (extra __syncthreads before LDS reuse — the loop no
// longer ends with a barrier).
// ---------------------------------------------------------------------------
#define ATILE (256 * 32)
#define BTILE (128 * 32)

template <int MODE>
__global__ __launch_bounds__(512)
void gemm_kernel(const __hip_bfloat16* __restrict__ A,
                 const __hip_bfloat16* __restrict__ BT,
                 const float* __restrict__ bias,
                 float* __restrict__ out,
                 __hip_bfloat16* __restrict__ qbuf,
                 __hip_bfloat16* __restrict__ kbuf,
                 __hip_bfloat16* __restrict__ vtbuf,
                 const float* __restrict__ ropetab,
                 int M, int N, int K) {
    // [0..3*ATILE): A triple-buffer; [3*ATILE..): B triple-buffer. 72 KB.
    __shared__ __align__(16) __hip_bfloat16 GS[3 * ATILE + 3 * BTILE];

    const int tid  = threadIdx.x;
    const int lane = tid & 63;
    const int wave = tid >> 6;          // 0..7
    const int wm   = wave >> 1;         // 0..3 (m quadrant)
    const int wn   = wave & 1;          // 0..1 (n half)
    const int l15  = lane & 15;
    const int quad = lane >> 4;

    const int nT  = N >> 7;
    const int grp = blockIdx.x / (8 * nT);
    const int rem = blockIdx.x - grp * 8 * nT;
    const int m0  = (grp * 8 + (rem & 7)) * 256;
    const int n0  = (rem >> 3) * 128;

    f32x4_t acc[4][4];
#pragma unroll
    for (int i = 0; i < 4; i++)
#pragma unroll
        for (int j = 0; j < 4; j++) acc[i][j] = (f32x4_t)0.0f;

    const int lrow = lane >> 2;
    // pre-swizzled source chunk: LDS[row][p] holds global chunk p^((row>>2)&3)
    const int scol = ((lane & 3) ^ ((lane >> 4) & 3)) * 8;
    const __hip_bfloat16* gA  = A  + (size_t)(m0 + wave * 32 + lrow) * K + scol;
    const __hip_bfloat16* gA2 = gA + (size_t)16 * K;
    const __hip_bfloat16* gB  = BT + (size_t)(n0 + wave * 16 + lrow) * K + scol;
    const int ldsA = wave * 32 * 32;   // this wave's A rows (elements)
    const int ldsB = wave * 16 * 32;   // this wave's B rows (elements)

    const int NK = K >> 5;
    // prologue: stage K-tiles 0,1 into buffers 0,1
    GLOAD_LDS16(gA,  GS + ldsA);
    GLOAD_LDS16(gA2, GS + ldsA + 16 * 32);
    GLOAD_LDS16(gB,  GS + 3 * ATILE + ldsB);
    if (NK > 1) {
        GLOAD_LDS16(gA  + 32, GS + ATILE + ldsA);
        GLOAD_LDS16(gA2 + 32, GS + ATILE + ldsA + 16 * 32);
        GLOAD_LDS16(gB  + 32, GS + 3 * ATILE + BTILE + ldsB);
    }

    int cur = 0;   // buffer slot of tile t
    int pre = 2;   // buffer slot of tile t+2
    for (int t = 0; t < NK; ++t) {
        if (t + 1 < NK) {
            // tile t drained; tile t+1's 3 loads may remain in flight
            asm volatile("s_waitcnt vmcnt(3)" ::: "memory");
        } else {
            asm volatile("s_waitcnt vmcnt(0)" ::: "memory");
        }
        __builtin_amdgcn_s_barrier();            // iter t-1 reads complete everywhere
        __builtin_amdgcn_sched_barrier(0);       // pin: nothing hoists above

        if (t + 2 < NK) {
            const int kk = (t + 2) << 5;
            GLOAD_LDS16(gA  + kk, GS + pre * ATILE + ldsA);
            GLOAD_LDS16(gA2 + kk, GS + pre * ATILE + ldsA + 16 * 32);
            GLOAD_LDS16(gB  + kk, GS + 3 * ATILE + pre * BTILE + ldsB);
            __builtin_amdgcn_sched_barrier(0);   // pin: DMA issues stay early
        }

        const int Ab = cur * ATILE;
        const int Bb = 3 * ATILE + cur * BTILE;
        bf16x8_t af[4], bfv[4];
#pragma unroll
        for (int i = 0; i < 4; i++)
            af[i] = *(const bf16x8_t*)(GS + Ab + (wm * 64 + i * 16 + l15) * 32 +
                                       ((quad ^ (l15 >> 2)) * 8));
#pragma unroll
        for (int j = 0; j < 4; j++)
            bfv[j] = *(const bf16x8_t*)(GS + Bb + (wn * 64 + j * 16 + l15) * 32 +
                                        ((quad ^ (l15 >> 2)) * 8));
#pragma unroll
        for (int i = 0; i < 4; i++)
#pragma unroll
            for (int j = 0; j < 4; j++)
                acc[i][j] = __builtin_amdgcn_mfma_f32_16x16x32_bf16(af[i], bfv[j], acc[i][j], 0, 0, 0);

        cur = (cur == 2) ? 0 : cur + 1;
        pre = (pre == 2) ? 0 : pre + 1;
    }

    float bv[4];
#pragma unroll
    for (int j = 0; j < 4; j++)
        bv[j] = bias[n0 + wn * 64 + j * 16 + l15];

    if (MODE == 0) {
#pragma unroll
        for (int i = 0; i < 4; i++)
#pragma unroll
            for (int r = 0; r < 4; r++) {
                int row = m0 + wm * 64 + i * 16 + quad * 4 + r;
#pragma unroll
                for (int j = 0; j < 4; j++) {
                    int col = n0 + wn * 64 + j * 16 + l15;
                    out[(size_t)row * N + col] = acc[i][j][r] + bv[j];
                }
            }
    } else {
        const int cb   = n0 + wn * 64;
        const int part = cb >> 10;           // 0=q 1=k 2=v  (uniform per block:
                                             // n0 is a multiple of 128, so no
                                             // block straddles the 1024/2048
                                             // boundaries)
        if (part == 2) {
            // V: transpose 256 tokens x 128 d (2 heads) through LDS in two
            // 128-token passes; region L=[128 d][136] (pad) fits 72KB GS.
            __syncthreads();                     // loop has no tail barrier:
                                                 // wait all waves' last reads
            const int hb = (n0 & 1023) >> 6;     // even head base
            const int bb = m0 >> 11;
            const int t0 = m0 & 2047;            // multiple of 256
            __hip_bfloat16* L = GS;
#pragma unroll
            for (int p = 0; p < 2; ++p) {
                if ((wm >> 1) == p) {            // waves owning this 128-token half
#pragma unroll
                    for (int j = 0; j < 4; j++) {
                        int d = wn * 64 + j * 16 + l15;
#pragma unroll
                        for (int i = 0; i < 4; i++) {
                            int rtb = (wm & 1) * 64 + i * 16 + quad * 4;
                            uint2 pk;
                            pk.x = pack2bf(acc[i][j][0] + bv[j], acc[i][j][1] + bv[j]);
                            pk.y = pack2bf(acc[i][j][2] + bv[j], acc[i][j][3] + bv[j]);
                            *(uint2*)(L + d * 136 + rtb) = pk;
                        }
                    }
                }
                __syncthreads();
                {
                    int row = tid >> 2;          // 0..127 = (head-off<<6)|dd
                    int hb2 = hb + (row >> 6);
                    int dd  = row & 63;
                    const __hip_bfloat16* src = L + row * 136;
                    __hip_bfloat16* dstv = vtbuf +
                        ((size_t)((bb * H_ + hb2) * D_ + dd)) * T_ + t0 + p * 128;
#pragma unroll
                    for (int s2 = 0; s2 < 4; s2++) {
                        int ch = (tid & 3) + s2 * 4;
                        *(bf16x8_t*)(dstv + ch * 8) = *(const bf16x8_t*)(src + ch * 8);
                    }
                }
                if (p == 0) __syncthreads();     // WAR before pass-1 L writes
            }
        } else {
            const int h = (cb & 1023) >> 6;
            __hip_bfloat16* dst = (part == 0) ? qbuf : kbuf;
            // q: fold 1/sqrt(D) AND log2(e) so attention uses exp2 directly
            const float sc = (part == 0) ? 0.18033688011112042f : 1.0f;
#pragma unroll
            for (int i = 0; i < 4; i++) {
#pragma unroll
                for (int r = 0; r < 4; r++) {
                    int row = m0 + wm * 64 + i * 16 + quad * 4 + r;
                    int b = row >> 11;
                    int t = row & 2047;
                    const float* trow = ropetab + (size_t)row * 64;
                    size_t base = ((size_t)(b * H_ + h) * T_ + t) * D_;
#pragma unroll
                    for (int j = 0; j < 2; j++) {
                        int d = j * 16 + l15;
                        float cs = trow[d];
                        float sn = trow[32 + d];
                        float x1 = acc[i][j][r]     + bv[j];
                        float x2 = acc[i][j + 2][r] + bv[j + 2];
                        dst[base + d]      = __float2bfloat16(sc * (x1 * cs - x2 * sn));
                        dst[base + d + 32] = __float2bfloat16(sc * (x1 * sn + x2 * cs));
                    }
                }
            }
        }
    }
}

// ---------------------------------------------------------------------------
// Flash attention v10: v8 structure with ONE barrier per K/V tile:
//   vmcnt(0)  [tile t landed — only its 4 DMAs are in flight]
//   barrier   [all waves' iter t-1 reads are in registers]
//   issue tile t+1 -> buf nxt  [last read at iter t-1 -> safe]
//   compute   [no tail barrier, no lgkmcnt drain]
// Same 32 KB LDS, same 4 blocks/CU. __syncthreads added after the loop to
// protect the epilogue LDS reuse. Counted-vmcnt DMA, in-register P^T via
// permlane swaps, -SHIFT2 folded into MFMA C-in, setprio around MFMA.
// ---------------------------------------------------------------------------
#define KVTILE (64 * 64)

__global__ __launch_bounds__(256, 4)
void attn_kernel(const __hip_bfloat16* __restrict__ q,
                 const __hip_bfloat16* __restrict__ k,
                 const __hip_bfloat16* __restrict__ vt,
                 __hip_bfloat16* __restrict__ attn_out) {
    // [0..1]*KVTILE: K double-buffer; [2..3]*KVTILE: V double-buffer (32 KB).
    // After the loop (+barrier) the front is reused as the per-wave epilogue
    // staging area (4 waves x 32 x 72 bf16 = 18 KB <= 32 KB).
    __shared__ __align__(16) __hip_bfloat16 SMEM[4 * KVTILE];

    const int tid  = threadIdx.x;
    const int lane = tid & 63;
    const int wave = tid >> 6;
    const int l15  = lane & 15;
    const int quad = lane >> 4;
    const int x7   = l15 & 7;

    const int bh = blockIdx.x & 63;          // XCD swizzle
    const int qt = blockIdx.x >> 6;          // 0..15
    const int b  = bh >> 4;
    const int h  = bh & 15;

    const size_t qkbase = (size_t)bh * T_ * D_;
    const size_t vbase  = (size_t)bh * D_ * T_;
    const int    qrow0  = qt * 128 + wave * 32;

    // DMA lane mapping: lane = drow*8 + dchunk; fetch global chunk dchunk^drow
    const int drow   = lane >> 3;        // 0..7
    const int gchunk = (lane & 7) ^ drow;

    const __hip_bfloat16* kg = k + qkbase;
    const __hip_bfloat16* vg = vt + vbase;

    // fragment-read swizzled chunk offsets (elements)
    const int c0 = ((quad)     ^ x7) * 8;
    const int c1 = ((4 + quad) ^ x7) * 8;

    // Q as B-fragment (n=qrow, k=d), direct global (once)
    bf16x8_t qa[2][2];
#pragma unroll
    for (int qf = 0; qf < 2; qf++)
#pragma unroll
        for (int kk = 0; kk < 2; kk++)
            qa[qf][kk] = *(const bf16x8_t*)(q + qkbase +
                          (size_t)(qrow0 + qf * 16 + l15) * D_ + kk * 32 + quad * 8);

    // all-ones A-fragment for MFMA row-sums
    bf16x8_t ones;
#pragma unroll
    for (int i = 0; i < 8; i++) ones[i] = (short)0x3F80;

    // loop-invariant C-operand: folds the -SHIFT2 softmax bias into the MFMA
    const f32x4_t mbias = (f32x4_t)(-SHIFT2);

    f32x4_t o[2][4];
#pragma unroll
    for (int qf = 0; qf < 2; qf++)
#pragma unroll
        for (int jd = 0; jd < 4; jd++) o[qf][jd] = (f32x4_t)0.0f;
    f32x4_t osum[2];
    osum[0] = (f32x4_t)0.0f;
    osum[1] = (f32x4_t)0.0f;

    // prologue: stage tile 0 into buffer 0 (iter-0 vmcnt+barrier syncs it)
#pragma unroll
    for (int i = 0; i < 2; i++) {
        int r = wave * 16 + i * 8;
        GLOAD_LDS16(kg + (size_t)(r + drow) * D_ + gchunk * 8, SMEM + r * 64);
        GLOAD_LDS16(vg + (size_t)(r + drow) * T_ + gchunk * 8, SMEM + 2 * KVTILE + r * 64);
    }

    for (int kt = 0; kt < T_ / 64; kt++) {
        const int curoff = (kt & 1) * KVTILE;
        const int nxtoff = curoff ^ KVTILE;

        asm volatile("s_waitcnt vmcnt(0)" ::: "memory");  // tile kt landed
        __builtin_amdgcn_s_barrier();            // iter kt-1 reads complete everywhere
        __builtin_amdgcn_sched_barrier(0);       // pin: nothing hoists above

        // issue next tile's DMA now; buf nxt was last read at iter kt-1
        if (kt + 1 < T_ / 64) {
#pragma unroll
            for (int i = 0; i < 2; i++) {
                int r = wave * 16 + i * 8;
                GLOAD_LDS16(kg + (size_t)((kt + 1) * 64 + r + drow) * D_ + gchunk * 8,
                            SMEM + nxtoff + r * 64);
                GLOAD_LDS16(vg + (size_t)(r + drow) * T_ + (kt + 1) * 64 + gchunk * 8,
                            SMEM + 2 * KVTILE + nxtoff + r * 64);
            }
            __builtin_amdgcn_sched_barrier(0);   // pin: DMA issues stay early
        }

        const __hip_bfloat16* KLc = SMEM + curoff;
        const __hip_bfloat16* VLc = SMEM + 2 * KVTILE + curoff;

        // K fragments (swizzled), then S^T = K.Q^T - SHIFT2 (bias via C-in)
        bf16x8_t kf[4][2];
#pragma unroll
        for (int jt = 0; jt < 4; jt++) {
            kf[jt][0] = *(const bf16x8_t*)(KLc + (jt * 16 + l15) * 64 + c0);
            kf[jt][1] = *(const bf16x8_t*)(KLc + (jt * 16 + l15) * 64 + c1);
        }

        f32x4_t sT[2][4];
        __builtin_amdgcn_s_setprio(1);
#pragma unroll
        for (int jt = 0; jt < 4; jt++)
#pragma unroll
            for (int qf = 0; qf < 2; qf++) {
                sT[qf][jt] = __builtin_amdgcn_mfma_f32_16x16x32_bf16(
                    kf[jt][0], qa[qf][0], mbias, 0, 0, 0);
                sT[qf][jt] = __builtin_amdgcn_mfma_f32_16x16x32_bf16(
                    kf[jt][1], qa[qf][1], sT[qf][jt], 0, 0, 0);
            }
        __builtin_amdgcn_s_setprio(0);

        // p = exp2(s'); pack to bf16 pairs, then build P^T B-fragments
        // entirely in registers via permlane swaps (no LDS round-trip).
        bf16x8_t pb[2][2];
#pragma unroll
        for (int qf = 0; qf < 2; qf++) {
            unsigned int w0[4], w1[4];
#pragma unroll
            for (int jt = 0; jt < 4; jt++) {
                float p0 = __builtin_amdgcn_exp2f(sT[qf][jt][0]);
                float p1 = __builtin_amdgcn_exp2f(sT[qf][jt][1]);
                float p2 = __builtin_amdgcn_exp2f(sT[qf][jt][2]);
                float p3 = __builtin_amdgcn_exp2f(sT[qf][jt][3]);
                w0[jt] = pack2bf(p0, p1);   // keys quad*4+0, +1
                w1[jt] = pack2bf(p2, p3);   // keys quad*4+2, +3
            }
#pragma unroll
            for (int kk = 0; kk < 2; kk++) {
                uiv2_t s0 = __builtin_amdgcn_permlane32_swap(w0[2 * kk], w0[2 * kk + 1], false, false);
                uiv2_t r0 = __builtin_amdgcn_permlane16_swap(s0[0], s0[1], false, false);
                uiv2_t s1 = __builtin_amdgcn_permlane32_swap(w1[2 * kk], w1[2 * kk + 1], false, false);
                uiv2_t r1 = __builtin_amdgcn_permlane16_swap(s1[0], s1[1], false, false);
                union { unsigned int u[4]; bf16x8_t v; } pu;
                pu.u[0] = r0[0];   // keys +0,1
                pu.u[1] = r1[0];   // keys +2,3
                pu.u[2] = r0[1];   // keys +4,5
                pu.u[3] = r1[1];   // keys +6,7
                pb[qf][kk] = pu.v;
            }
        }

        __builtin_amdgcn_s_setprio(1);
        // row-sums via ones-MFMA: every D row = sum_k P[n][k]
#pragma unroll
        for (int qf = 0; qf < 2; qf++) {
            osum[qf] = __builtin_amdgcn_mfma_f32_16x16x32_bf16(ones, pb[qf][0], osum[qf], 0, 0, 0);
            osum[qf] = __builtin_amdgcn_mfma_f32_16x16x32_bf16(ones, pb[qf][1], osum[qf], 0, 0, 0);
        }

        // o^T += V^T.P^T
#pragma unroll
        for (int jd = 0; jd < 4; jd++) {
            bf16x8_t vf0 = *(const bf16x8_t*)(VLc + (jd * 16 + l15) * 64 + c0);
            bf16x8_t vf1 = *(const bf16x8_t*)(VLc + (jd * 16 + l15) * 64 + c1);
#pragma unroll
            for (int qf = 0; qf < 2; qf++) {
                o[qf][jd] = __builtin_amdgcn_mfma_f32_16x16x32_bf16(vf0, pb[qf][0], o[qf][jd], 0, 0, 0);
                o[qf][jd] = __builtin_amdgcn_mfma_f32_16x16x32_bf16(vf1, pb[qf][1], o[qf][jd], 0, 0, 0);
            }
        }
        __builtin_amdgcn_s_setprio(0);
        // no tail barrier: next iter's vmcnt(0)+barrier provides the sync
    }

    // per-qrow inverse sums (all lanes/quads hold the value for their l15)
    float inv[2];
    inv[0] = 1.0f / osum[0][0];
    inv[1] = 1.0f / osum[1][0];

    // epilogue staging: the loop has no tail barrier, so wait for all waves'
    // last-tile reads before overwriting the K/V buffers
    __syncthreads();
    __hip_bfloat16* Pep = SMEM + wave * (32 * 72);

    // o^T -> LDS (packed b64), then coalesced 16B store
#pragma unroll
    for (int qf = 0; qf < 2; qf++) {
#pragma unroll
        for (int jd = 0; jd < 4; jd++) {
            uint2 pk;
            pk.x = pack2bf(o[qf][jd][0] * inv[qf], o[qf][jd][1] * inv[qf]);
            pk.y = pack2bf(o[qf][jd][2] * inv[qf], o[qf][jd][3] * inv[qf]);
            *(uint2*)(Pep + (qf * 16 + l15) * 72 + jd * 16 + quad * 4) = pk;
        }
    }
    WAVE_ORDER();

#pragma unroll
    for (int rnd = 0; rnd < 4; rnd++) {
        int row = rnd * 8 + (lane >> 3);
        int col = (lane & 7) * 8;
        bf16x8_t vrow = *(const bf16x8_t*)(Pep + row * 72 + col);
        int token = qt * 128 + wave * 32 + row;
        *(bf16x8_t*)(attn_out + ((size_t)(b * T_ + token)) * C_ + h * 64 + col) = vrow;
    }
}

// ---------------------------------------------------------------------------
extern "C" void kernel_launch(void* const* d_in, const int* in_sizes, int n_in,
                              void* d_out, int out_size, void* d_ws, size_t ws_size,
                              hipStream_t stream) {
    const float* x        = (const float*)d_in[0];
    const int*   keep_idx = (const int*)d_in[1];
    const int*   orig_len = (const int*)d_in[2];
    const float* Wqkv     = (const float*)d_in[3];
    const float* bqkv     = (const float*)d_in[4];
    const float* Wproj    = (const float*)d_in[5];
    const float* bproj    = (const float*)d_in[6];
    float*       out      = (float*)d_out;

    const size_t NTOK = (size_t)B_ * T_;
    const size_t QKV1 = NTOK * C_;

    __hip_bfloat16* qbuf    = (__hip_bfloat16*)d_ws;
    __hip_bfloat16* kbuf    = qbuf    + QKV1;
    __hip_bfloat16* vtbuf   = kbuf    + QKV1;
    __hip_bfloat16* attnbuf = vtbuf   + QKV1;
    __hip_bfloat16* WqkvT   = attnbuf + QKV1;
    __hip_bfloat16* WprojT  = WqkvT   + (size_t)C_ * 3 * C_;
    __hip_bfloat16* xbf     = WprojT  + (size_t)C_ * C_;
    float*          ropetab = (float*)(xbf + QKV1);

    // fused prep: xconv (8192) + rope (1024) + WqkvT (3072) + WprojT (1024)
    prep_kernel<<<13312, 256, 0, stream>>>(x, xbf, keep_idx, orig_len, ropetab,
                                           Wqkv, WqkvT, Wproj, WprojT);

    gemm_kernel<1><<<(8192 / 256) * (3072 / 128), 512, 0, stream>>>(
        xbf, WqkvT, bqkv, nullptr, qbuf, kbuf, vtbuf, ropetab, 8192, 3072, 1024);

    attn_kernel<<<(T_ / 128) * 64, 256, 0, stream>>>(qbuf, kbuf, vtbuf, attnbuf);

    gemm_kernel<0><<<(8192 / 256) * (1024 / 128), 512, 0, stream>>>(
        attnbuf, WprojT, bproj, out, nullptr, nullptr, nullptr, nullptr, 8192, 1024, 1024);
}

// Round 11
// 260.855 us; speedup vs baseline: 1.0874x; 1.0047x over previous
//
#include <hip/hip_runtime.h>
#include <hip/hip_bf16.h>
#include <math.h>

#define B_ 4
#define T_ 2048
#define C_ 1024
#define H_ 16
#define D_ 64

typedef __attribute__((ext_vector_type(8))) short bf16x8_t;   // 8 bf16 (4 VGPRs)
typedef __attribute__((ext_vector_type(4))) float f32x4_t;
typedef __attribute__((ext_vector_type(2))) unsigned int uiv2_t;

// q is pre-scaled by 0.125*log2(e) in the QKV epilogue, so scores arrive in
// base-2: p = exp2(s' - SHIFT2). |s|<=~8 => |s'|<=11.6; SHIFT2=32 keeps
// everything finite-positive; normalization cancels the shift exactly.
// The -SHIFT2 bias rides in as the C-operand of the first MFMA of each chain.
#define SHIFT2 32.0f

// async global->LDS DMA, 16B/lane; HW dest = wave-uniform lds base + lane*16
#define GLOAD_LDS16(gp, lp)                                                          \
    __builtin_amdgcn_global_load_lds(                                                \
        (const __attribute__((address_space(1))) void*)(gp),                         \
        (__attribute__((address_space(3))) void*)(lp), 16, 0, 0)

// compiler-only ordering (no instruction): per-wave LDS RAW relies on the
// in-order DS pipe (verified correct rounds 6-7)
#define WAVE_ORDER() __builtin_amdgcn_wave_barrier()

__device__ inline unsigned int pack2bf(float a, float b) {
    __hip_bfloat162 h = __float22bfloat162_rn(make_float2(a, b));  // v_cvt_pk_bf16_f32
    return *reinterpret_cast<unsigned int*>(&h);
}

// ---------------------------------------------------------------------------
// Fused prep: one launch replaces {xconv, rope_tab, Wqkv-transpose,
// Wproj-transpose}. Block-uniform branch on blockIdx ranges.
//   [0, 8192)          xconv: x f32 -> bf16, 4 el/thread
//   [8192, 9216)       rope table: tab[token][0..31]=cos, [32..63]=sin
//   [9216, 12288)      Wqkv^T  (1024x3072 -> 3072x1024 bf16)
//   [12288, 13312)     Wproj^T (1024x1024 -> 1024x1024 bf16)
// ---------------------------------------------------------------------------
__global__ __launch_bounds__(256)
void prep_kernel(const float* __restrict__ x, __hip_bfloat16* __restrict__ xbf,
                 const int* __restrict__ keep, const int* __restrict__ orig,
                 float* __restrict__ tab,
                 const float* __restrict__ Wqkv, __hip_bfloat16* __restrict__ WqkvT,
                 const float* __restrict__ Wproj, __hip_bfloat16* __restrict__ WprojT) {
    __shared__ float s[32][33];
    const int bid = blockIdx.x;
    const int tid = threadIdx.x;

    if (bid < 8192) {
        int i = bid * 256 + tid;
        float4 v = *(const float4*)(x + (size_t)i * 4);
        uint2 u;
        u.x = pack2bf(v.x, v.y);
        u.y = pack2bf(v.z, v.w);
        *(uint2*)(xbf + (size_t)i * 4) = u;
    } else if (bid < 9216) {
        int i = (bid - 8192) * 256 + tid;
        int tok = i >> 5, d = i & 31;
        float freq = 0.5f * exp2f((float)d * (6.321928094887362f / 31.0f));
        float ang  = 6.283185307179586f * ((float)keep[tok] / (float)(*orig)) * freq;
        tab[(size_t)tok * 64 + d]      = cosf(ang);
        tab[(size_t)tok * 64 + 32 + d] = sinf(ang);
    } else {
        const float* in;
        __hip_bfloat16* outp;
        int N, n0, k0, r;
        if (bid < 12288) {
            r = bid - 9216;                 // Wqkv: grid (96, 32)
            in = Wqkv; outp = WqkvT; N = 3 * C_;
            n0 = (r % 96) * 32; k0 = (r / 96) * 32;
        } else {
            r = bid - 12288;                // Wproj: grid (32, 32)
            in = Wproj; outp = WprojT; N = C_;
            n0 = (r % 32) * 32; k0 = (r / 32) * 32;
        }
        const int K = C_;
        const int tx = tid & 31;
        const int ty = tid >> 5;            // 0..7
#pragma unroll
        for (int yy = 0; yy < 32; yy += 8)
            s[ty + yy][tx] = in[(size_t)(k0 + ty + yy) * N + n0 + tx];
        __syncthreads();
#pragma unroll
        for (int yy = 0; yy < 32; yy += 8)
            outp[(size_t)(n0 + ty + yy) * K + k0 + tx] = __float2bfloat16(s[tx][ty + yy]);
    }
}

// ---------------------------------------------------------------------------
// GEMM 256x128 tile, 8 waves (512 thr), BK=32, TRIPLE-BUFFERED staging with
// ONE barrier per K-step (round-9 structure, unchanged):
//   vmcnt(3|0) -> barrier -> issue tile t+2 -> compute tile t
// LDS 72 KB, 2 blocks/CU, LDS XOR swizzle (T2, both-sides).
// MODE 0: f32 store. MODE 1: qkv epilogue; V transposed through LDS in
// two 128-token passes.
// ---------------------------------------------------------------------------
#define ATILE (256 * 32)
#define BTILE (128 * 32)

template <int MODE>
__global__ __launch_bounds__(512)
void gemm_kernel(const __hip_bfloat16* __restrict__ A,
                 const __hip_bfloat16* __restrict__ BT,
                 const float* __restrict__ bias,
                 float* __restrict__ out,
                 __hip_bfloat16* __restrict__ qbuf,
                 __hip_bfloat16* __restrict__ kbuf,
                 __hip_bfloat16* __restrict__ vtbuf,
                 const float* __restrict__ ropetab,
                 int M, int N, int K) {
    // [0..3*ATILE): A triple-buffer; [3*ATILE..): B triple-buffer. 72 KB.
    __shared__ __align__(16) __hip_bfloat16 GS[3 * ATILE + 3 * BTILE];

    const int tid  = threadIdx.x;
    const int lane = tid & 63;
    const int wave = tid >> 6;          // 0..7
    const int wm   = wave >> 1;         // 0..3 (m quadrant)
    const int wn   = wave & 1;          // 0..1 (n half)
    const int l15  = lane & 15;
    const int quad = lane >> 4;

    const int nT  = N >> 7;
    const int grp = blockIdx.x / (8 * nT);
    const int rem = blockIdx.x - grp * 8 * nT;
    const int m0  = (grp * 8 + (rem & 7)) * 256;
    const int n0  = (rem >> 3) * 128;

    f32x4_t acc[4][4];
#pragma unroll
    for (int i = 0; i < 4; i++)
#pragma unroll
        for (int j = 0; j < 4; j++) acc[i][j] = (f32x4_t)0.0f;

    const int lrow = lane >> 2;
    // pre-swizzled source chunk: LDS[row][p] holds global chunk p^((row>>2)&3)
    const int scol = ((lane & 3) ^ ((lane >> 4) & 3)) * 8;
    const __hip_bfloat16* gA  = A  + (size_t)(m0 + wave * 32 + lrow) * K + scol;
    const __hip_bfloat16* gA2 = gA + (size_t)16 * K;
    const __hip_bfloat16* gB  = BT + (size_t)(n0 + wave * 16 + lrow) * K + scol;
    const int ldsA = wave * 32 * 32;   // this wave's A rows (elements)
    const int ldsB = wave * 16 * 32;   // this wave's B rows (elements)

    const int NK = K >> 5;
    // prologue: stage K-tiles 0,1 into buffers 0,1
    GLOAD_LDS16(gA,  GS + ldsA);
    GLOAD_LDS16(gA2, GS + ldsA + 16 * 32);
    GLOAD_LDS16(gB,  GS + 3 * ATILE + ldsB);
    if (NK > 1) {
        GLOAD_LDS16(gA  + 32, GS + ATILE + ldsA);
        GLOAD_LDS16(gA2 + 32, GS + ATILE + ldsA + 16 * 32);
        GLOAD_LDS16(gB  + 32, GS + 3 * ATILE + BTILE + ldsB);
    }

    int cur = 0;   // buffer slot of tile t
    int pre = 2;   // buffer slot of tile t+2
    for (int t = 0; t < NK; ++t) {
        if (t + 1 < NK) {
            // tile t drained; tile t+1's 3 loads may remain in flight
            asm volatile("s_waitcnt vmcnt(3)" ::: "memory");
        } else {
            asm volatile("s_waitcnt vmcnt(0)" ::: "memory");
        }
        __builtin_amdgcn_s_barrier();            // iter t-1 reads complete everywhere
        __builtin_amdgcn_sched_barrier(0);       // pin: nothing hoists above

        if (t + 2 < NK) {
            const int kk = (t + 2) << 5;
            GLOAD_LDS16(gA  + kk, GS + pre * ATILE + ldsA);
            GLOAD_LDS16(gA2 + kk, GS + pre * ATILE + ldsA + 16 * 32);
            GLOAD_LDS16(gB  + kk, GS + 3 * ATILE + pre * BTILE + ldsB);
            __builtin_amdgcn_sched_barrier(0);   // pin: DMA issues stay early
        }

        const int Ab = cur * ATILE;
        const int Bb = 3 * ATILE + cur * BTILE;
        bf16x8_t af[4], bfv[4];
#pragma unroll
        for (int i = 0; i < 4; i++)
            af[i] = *(const bf16x8_t*)(GS + Ab + (wm * 64 + i * 16 + l15) * 32 +
                                       ((quad ^ (l15 >> 2)) * 8));
#pragma unroll
        for (int j = 0; j < 4; j++)
            bfv[j] = *(const bf16x8_t*)(GS + Bb + (wn * 64 + j * 16 + l15) * 32 +
                                        ((quad ^ (l15 >> 2)) * 8));
#pragma unroll
        for (int i = 0; i < 4; i++)
#pragma unroll
            for (int j = 0; j < 4; j++)
                acc[i][j] = __builtin_amdgcn_mfma_f32_16x16x32_bf16(af[i], bfv[j], acc[i][j], 0, 0, 0);

        cur = (cur == 2) ? 0 : cur + 1;
        pre = (pre == 2) ? 0 : pre + 1;
    }

    float bv[4];
#pragma unroll
    for (int j = 0; j < 4; j++)
        bv[j] = bias[n0 + wn * 64 + j * 16 + l15];

    if (MODE == 0) {
#pragma unroll
        for (int i = 0; i < 4; i++)
#pragma unroll
            for (int r = 0; r < 4; r++) {
                int row = m0 + wm * 64 + i * 16 + quad * 4 + r;
#pragma unroll
                for (int j = 0; j < 4; j++) {
                    int col = n0 + wn * 64 + j * 16 + l15;
                    out[(size_t)row * N + col] = acc[i][j][r] + bv[j];
                }
            }
    } else {
        const int cb   = n0 + wn * 64;
        const int part = cb >> 10;           // 0=q 1=k 2=v  (uniform per block:
                                             // n0 is a multiple of 128, so no
                                             // block straddles the 1024/2048
                                             // boundaries)
        if (part == 2) {
            // V: transpose 256 tokens x 128 d (2 heads) through LDS in two
            // 128-token passes; region L=[128 d][136] (pad) fits 72KB GS.
            __syncthreads();                     // loop has no tail barrier:
                                                 // wait all waves' last reads
            const int hb = (n0 & 1023) >> 6;     // even head base
            const int bb = m0 >> 11;
            const int t0 = m0 & 2047;            // multiple of 256
            __hip_bfloat16* L = GS;
#pragma unroll
            for (int p = 0; p < 2; ++p) {
                if ((wm >> 1) == p) {            // waves owning this 128-token half
#pragma unroll
                    for (int j = 0; j < 4; j++) {
                        int d = wn * 64 + j * 16 + l15;
#pragma unroll
                        for (int i = 0; i < 4; i++) {
                            int rtb = (wm & 1) * 64 + i * 16 + quad * 4;
                            uint2 pk;
                            pk.x = pack2bf(acc[i][j][0] + bv[j], acc[i][j][1] + bv[j]);
                            pk.y = pack2bf(acc[i][j][2] + bv[j], acc[i][j][3] + bv[j]);
                            *(uint2*)(L + d * 136 + rtb) = pk;
                        }
                    }
                }
                __syncthreads();
                {
                    int row = tid >> 2;          // 0..127 = (head-off<<6)|dd
                    int hb2 = hb + (row >> 6);
                    int dd  = row & 63;
                    const __hip_bfloat16* src = L + row * 136;
                    __hip_bfloat16* dstv = vtbuf +
                        ((size_t)((bb * H_ + hb2) * D_ + dd)) * T_ + t0 + p * 128;
#pragma unroll
                    for (int s2 = 0; s2 < 4; s2++) {
                        int ch = (tid & 3) + s2 * 4;
                        *(bf16x8_t*)(dstv + ch * 8) = *(const bf16x8_t*)(src + ch * 8);
                    }
                }
                if (p == 0) __syncthreads();     // WAR before pass-1 L writes
            }
        } else {
            const int h = (cb & 1023) >> 6;
            __hip_bfloat16* dst = (part == 0) ? qbuf : kbuf;
            // q: fold 1/sqrt(D) AND log2(e) so attention uses exp2 directly
            const float sc = (part == 0) ? 0.18033688011112042f : 1.0f;
#pragma unroll
            for (int i = 0; i < 4; i++) {
#pragma unroll
                for (int r = 0; r < 4; r++) {
                    int row = m0 + wm * 64 + i * 16 + quad * 4 + r;
                    int b = row >> 11;
                    int t = row & 2047;
                    const float* trow = ropetab + (size_t)row * 64;
                    size_t base = ((size_t)(b * H_ + h) * T_ + t) * D_;
#pragma unroll
                    for (int j = 0; j < 2; j++) {
                        int d = j * 16 + l15;
                        float cs = trow[d];
                        float sn = trow[32 + d];
                        float x1 = acc[i][j][r]     + bv[j];
                        float x2 = acc[i][j + 2][r] + bv[j + 2];
                        dst[base + d]      = __float2bfloat16(sc * (x1 * cs - x2 * sn));
                        dst[base + d + 32] = __float2bfloat16(sc * (x1 * sn + x2 * cs));
                    }
                }
            }
        }
    }
}

// ---------------------------------------------------------------------------
// Flash attention v11: 8 waves/block (512 thr, 512 blocks) + QUAD-buffered
// K/V ring, prefetch issued 3 tiles ahead:
//   vmcnt(4)  [tiles kt+1,kt+2 in flight (2 loads each); tile kt landed —
//              the waited-on tile was issued THREE iterations ago]
//   barrier   [iter kt-1 reads complete everywhere]
//   issue tile kt+3 -> slot (kt+3)%4  [= slot kt-1, last read at iter kt-1]
//   compute   [no tail barrier]
// vs v10: per-wave staging halves (1 K + 1 V load/tile), K/V HBM re-read
// halves (8 qt-readers/head not 16), and the per-iter DMA drain is covered
// by a 3-iteration window instead of 1. Occupancy unchanged: 2 blocks x
// 8 waves = 16 waves/CU (LDS 64 KB, VGPR ~64). Per-wave compute (permlane
// P^T, mbias C-in, setprio) identical to v8/v10.
// ---------------------------------------------------------------------------
#define KVT 4096   // one 64x64 bf16 tile (elements)

__global__ __launch_bounds__(512, 4)
void attn_kernel(const __hip_bfloat16* __restrict__ q,
                 const __hip_bfloat16* __restrict__ k,
                 const __hip_bfloat16* __restrict__ vt,
                 __hip_bfloat16* __restrict__ attn_out) {
    // [0..4*KVT): K ring; [4*KVT..8*KVT): V ring (64 KB total).
    // After the loop (+syncthreads) the front is reused as the per-wave
    // epilogue staging area (8 waves x 32 x 72 bf16 = 36 KB <= 64 KB).
    __shared__ __align__(16) __hip_bfloat16 SMEM[8 * KVT];

    const int tid  = threadIdx.x;
    const int lane = tid & 63;
    const int wave = tid >> 6;           // 0..7
    const int l15  = lane & 15;
    const int quad = lane >> 4;
    const int x7   = l15 & 7;

    const int bh = blockIdx.x & 63;          // XCD swizzle (same-XCD per head)
    const int qt = blockIdx.x >> 6;          // 0..7
    const int b  = bh >> 4;
    const int h  = bh & 15;

    const size_t qkbase = (size_t)bh * T_ * D_;
    const size_t vbase  = (size_t)bh * D_ * T_;
    const int    qrow0  = qt * 256 + wave * 32;

    // DMA lane mapping: lane = drow*8 + dchunk; fetch global chunk dchunk^drow
    const int drow   = lane >> 3;        // 0..7
    const int gchunk = (lane & 7) ^ drow;
    const int r      = wave * 8;         // this wave's 8 rows of the 64-row tile

    const __hip_bfloat16* kg = k + qkbase;
    const __hip_bfloat16* vg = vt + vbase;

    // fragment-read swizzled chunk offsets (elements)
    const int c0 = ((quad)     ^ x7) * 8;
    const int c1 = ((4 + quad) ^ x7) * 8;

    // Q as B-fragment (n=qrow, k=d), direct global (once)
    bf16x8_t qa[2][2];
#pragma unroll
    for (int qf = 0; qf < 2; qf++)
#pragma unroll
        for (int kk = 0; kk < 2; kk++)
            qa[qf][kk] = *(const bf16x8_t*)(q + qkbase +
                          (size_t)(qrow0 + qf * 16 + l15) * D_ + kk * 32 + quad * 8);

    // all-ones A-fragment for MFMA row-sums
    bf16x8_t ones;
#pragma unroll
    for (int i = 0; i < 8; i++) ones[i] = (short)0x3F80;

    // loop-invariant C-operand: folds the -SHIFT2 softmax bias into the MFMA
    const f32x4_t mbias = (f32x4_t)(-SHIFT2);

    f32x4_t o[2][4];
#pragma unroll
    for (int qf = 0; qf < 2; qf++)
#pragma unroll
        for (int jd = 0; jd < 4; jd++) o[qf][jd] = (f32x4_t)0.0f;
    f32x4_t osum[2];
    osum[0] = (f32x4_t)0.0f;
    osum[1] = (f32x4_t)0.0f;

    // prologue: stage tiles 0,1,2 into ring slots 0,1,2 (2 loads/wave each)
#pragma unroll
    for (int tt = 0; tt < 3; ++tt) {
        GLOAD_LDS16(kg + (size_t)(tt * 64 + r + drow) * D_ + gchunk * 8,
                    SMEM + tt * KVT + r * 64);
        GLOAD_LDS16(vg + (size_t)(r + drow) * T_ + tt * 64 + gchunk * 8,
                    SMEM + 4 * KVT + tt * KVT + r * 64);
    }

    const int NT = T_ / 64;   // 32
    for (int kt = 0; kt < NT; kt++) {
        // tile kt landed; kt+1/kt+2 (2 loads each) may remain in flight
        if (kt + 2 < NT) {
            asm volatile("s_waitcnt vmcnt(4)" ::: "memory");
        } else if (kt + 1 < NT) {
            asm volatile("s_waitcnt vmcnt(2)" ::: "memory");
        } else {
            asm volatile("s_waitcnt vmcnt(0)" ::: "memory");
        }
        __builtin_amdgcn_s_barrier();            // iter kt-1 reads complete everywhere
        __builtin_amdgcn_sched_barrier(0);       // pin: nothing hoists above

        // issue tile kt+3 -> slot (kt+3)%4 (= slot kt-1, read at iter kt-1)
        if (kt + 3 < NT) {
            const int slot = (kt + 3) & 3;
            GLOAD_LDS16(kg + (size_t)((kt + 3) * 64 + r + drow) * D_ + gchunk * 8,
                        SMEM + slot * KVT + r * 64);
            GLOAD_LDS16(vg + (size_t)(r + drow) * T_ + (kt + 3) * 64 + gchunk * 8,
                        SMEM + 4 * KVT + slot * KVT + r * 64);
            __builtin_amdgcn_sched_barrier(0);   // pin: DMA issues stay early
        }

        const __hip_bfloat16* KLc = SMEM + (kt & 3) * KVT;
        const __hip_bfloat16* VLc = SMEM + 4 * KVT + (kt & 3) * KVT;

        // K fragments (swizzled), then S^T = K.Q^T - SHIFT2 (bias via C-in)
        bf16x8_t kf[4][2];
#pragma unroll
        for (int jt = 0; jt < 4; jt++) {
            kf[jt][0] = *(const bf16x8_t*)(KLc + (jt * 16 + l15) * 64 + c0);
            kf[jt][1] = *(const bf16x8_t*)(KLc + (jt * 16 + l15) * 64 + c1);
        }

        f32x4_t sT[2][4];
        __builtin_amdgcn_s_setprio(1);
#pragma unroll
        for (int jt = 0; jt < 4; jt++)
#pragma unroll
            for (int qf = 0; qf < 2; qf++) {
                sT[qf][jt] = __builtin_amdgcn_mfma_f32_16x16x32_bf16(
                    kf[jt][0], qa[qf][0], mbias, 0, 0, 0);
                sT[qf][jt] = __builtin_amdgcn_mfma_f32_16x16x32_bf16(
                    kf[jt][1], qa[qf][1], sT[qf][jt], 0, 0, 0);
            }
        __builtin_amdgcn_s_setprio(0);

        // p = exp2(s'); pack to bf16 pairs, then build P^T B-fragments
        // entirely in registers via permlane swaps (no LDS round-trip).
        bf16x8_t pb[2][2];
#pragma unroll
        for (int qf = 0; qf < 2; qf++) {
            unsigned int w0[4], w1[4];
#pragma unroll
            for (int jt = 0; jt < 4; jt++) {
                float p0 = __builtin_amdgcn_exp2f(sT[qf][jt][0]);
                float p1 = __builtin_amdgcn_exp2f(sT[qf][jt][1]);
                float p2 = __builtin_amdgcn_exp2f(sT[qf][jt][2]);
                float p3 = __builtin_amdgcn_exp2f(sT[qf][jt][3]);
                w0[jt] = pack2bf(p0, p1);   // keys quad*4+0, +1
                w1[jt] = pack2bf(p2, p3);   // keys quad*4+2, +3
            }
#pragma unroll
            for (int kk = 0; kk < 2; kk++) {
                uiv2_t s0 = __builtin_amdgcn_permlane32_swap(w0[2 * kk], w0[2 * kk + 1], false, false);
                uiv2_t r0 = __builtin_amdgcn_permlane16_swap(s0[0], s0[1], false, false);
                uiv2_t s1 = __builtin_amdgcn_permlane32_swap(w1[2 * kk], w1[2 * kk + 1], false, false);
                uiv2_t r1 = __builtin_amdgcn_permlane16_swap(s1[0], s1[1], false, false);
                union { unsigned int u[4]; bf16x8_t v; } pu;
                pu.u[0] = r0[0];   // keys +0,1
                pu.u[1] = r1[0];   // keys +2,3
                pu.u[2] = r0[1];   // keys +4,5
                pu.u[3] = r1[1];   // keys +6,7
                pb[qf][kk] = pu.v;
            }
        }

        __builtin_amdgcn_s_setprio(1);
        // row-sums via ones-MFMA: every D row = sum_k P[n][k]
#pragma unroll
        for (int qf = 0; qf < 2; qf++) {
            osum[qf] = __builtin_amdgcn_mfma_f32_16x16x32_bf16(ones, pb[qf][0], osum[qf], 0, 0, 0);
            osum[qf] = __builtin_amdgcn_mfma_f32_16x16x32_bf16(ones, pb[qf][1], osum[qf], 0, 0, 0);
        }

        // o^T += V^T.P^T
#pragma unroll
        for (int jd = 0; jd < 4; jd++) {
            bf16x8_t vf0 = *(const bf16x8_t*)(VLc + (jd * 16 + l15) * 64 + c0);
            bf16x8_t vf1 = *(const bf16x8_t*)(VLc + (jd * 16 + l15) * 64 + c1);
#pragma unroll
            for (int qf = 0; qf < 2; qf++) {
                o[qf][jd] = __builtin_amdgcn_mfma_f32_16x16x32_bf16(vf0, pb[qf][0], o[qf][jd], 0, 0, 0);
                o[qf][jd] = __builtin_amdgcn_mfma_f32_16x16x32_bf16(vf1, pb[qf][1], o[qf][jd], 0, 0, 0);
            }
        }
        __builtin_amdgcn_s_setprio(0);
        // no tail barrier: next iter's vmcnt+barrier provides the sync
    }

    // per-qrow inverse sums (all lanes/quads hold the value for their l15)
    float inv[2];
    inv[0] = 1.0f / osum[0][0];
    inv[1] = 1.0f / osum[1][0];

    // epilogue staging: wait for all waves' last-tile reads before
    // overwriting the K/V ring
    __syncthreads();
    __hip_bfloat16* Pep = SMEM + wave * (32 * 72);

    // o^T -> LDS (packed b64), then coalesced 16B store
#pragma unroll
    for (int qf = 0; qf < 2; qf++) {
#pragma unroll
        for (int jd = 0; jd < 4; jd++) {
            uint2 pk;
            pk.x = pack2bf(o[qf][jd][0] * inv[qf], o[qf][jd][1] * inv[qf]);
            pk.y = pack2bf(o[qf][jd][2] * inv[qf], o[qf][jd][3] * inv[qf]);
            *(uint2*)(Pep + (qf * 16 + l15) * 72 + jd * 16 + quad * 4) = pk;
        }
    }
    WAVE_ORDER();

#pragma unroll
    for (int rnd = 0; rnd < 4; rnd++) {
        int row = rnd * 8 + (lane >> 3);
        int col = (lane & 7) * 8;
        bf16x8_t vrow = *(const bf16x8_t*)(Pep + row * 72 + col);
        int token = qt * 256 + wave * 32 + row;
        *(bf16x8_t*)(attn_out + ((size_t)(b * T_ + token)) * C_ + h * 64 + col) = vrow;
    }
}

// ---------------------------------------------------------------------------
extern "C" void kernel_launch(void* const* d_in, const int* in_sizes, int n_in,
                              void* d_out, int out_size, void* d_ws, size_t ws_size,
                              hipStream_t stream) {
    const float* x        = (const float*)d_in[0];
    const int*   keep_idx = (const int*)d_in[1];
    const int*   orig_len = (const int*)d_in[2];
    const float* Wqkv     = (const float*)d_in[3];
    const float* bqkv     = (const float*)d_in[4];
    const float* Wproj    = (const float*)d_in[5];
    const float* bproj    = (const float*)d_in[6];
    float*       out      = (float*)d_out;

    const size_t NTOK = (size_t)B_ * T_;
    const size_t QKV1 = NTOK * C_;

    __hip_bfloat16* qbuf    = (__hip_bfloat16*)d_ws;
    __hip_bfloat16* kbuf    = qbuf    + QKV1;
    __hip_bfloat16* vtbuf   = kbuf    + QKV1;
    __hip_bfloat16* attnbuf = vtbuf   + QKV1;
    __hip_bfloat16* WqkvT   = attnbuf + QKV1;
    __hip_bfloat16* WprojT  = WqkvT   + (size_t)C_ * 3 * C_;
    __hip_bfloat16* xbf     = WprojT  + (size_t)C_ * C_;
    float*          ropetab = (float*)(xbf + QKV1);

    // fused prep: xconv (8192) + rope (1024) + WqkvT (3072) + WprojT (1024)
    prep_kernel<<<13312, 256, 0, stream>>>(x, xbf, keep_idx, orig_len, ropetab,
                                           Wqkv, WqkvT, Wproj, WprojT);

    gemm_kernel<1><<<(8192 / 256) * (3072 / 128), 512, 0, stream>>>(
        xbf, WqkvT, bqkv, nullptr, qbuf, kbuf, vtbuf, ropetab, 8192, 3072, 1024);

    attn_kernel<<<(T_ / 256) * 64, 512, 0, stream>>>(qbuf, kbuf, vtbuf, attnbuf);

    gemm_kernel<0><<<(8192 / 256) * (1024 / 128), 512, 0, stream>>>(
        attnbuf, WprojT, bproj, out, nullptr, nullptr, nullptr, nullptr, 8192, 1024, 1024);
}

// Round 12
// 255.390 us; speedup vs baseline: 1.1106x; 1.0214x over previous
//
#include <hip/hip_runtime.h>
#include <hip/hip_bf16.h>
#include <math.h>

#define B_ 4
#define T_ 2048
#define C_ 1024
#define H_ 16
#define D_ 64

typedef __attribute__((ext_vector_type(8))) short bf16x8_t;   // 8 bf16 (4 VGPRs)
typedef __attribute__((ext_vector_type(4))) float f32x4_t;
typedef __attribute__((ext_vector_type(2))) unsigned int uiv2_t;

// q is pre-scaled by 0.125*log2(e) in the QKV epilogue, so scores arrive in
// base-2: p = exp2(s' - SHIFT2). |s|<=~8 => |s'|<=11.6; SHIFT2=32 keeps
// everything finite-positive; normalization cancels the shift exactly.
// The -SHIFT2 bias rides in as the C-operand of the first MFMA of each chain.
#define SHIFT2 32.0f

// async global->LDS DMA, 16B/lane; HW dest = wave-uniform lds base + lane*16
#define GLOAD_LDS16(gp, lp)                                                          \
    __builtin_amdgcn_global_load_lds(                                                \
        (const __attribute__((address_space(1))) void*)(gp),                         \
        (__attribute__((address_space(3))) void*)(lp), 16, 0, 0)

// compiler-only ordering (no instruction): per-wave LDS RAW relies on the
// in-order DS pipe (verified correct rounds 6-7)
#define WAVE_ORDER() __builtin_amdgcn_wave_barrier()

__device__ inline unsigned int pack2bf(float a, float b) {
    __hip_bfloat162 h = __float22bfloat162_rn(make_float2(a, b));  // v_cvt_pk_bf16_f32
    return *reinterpret_cast<unsigned int*>(&h);
}

// cross-quad sum for a value owned per-(quad,l15): after permlane32_swap the
// pair-sum t is 32-periodic; permlane16_swap then pairs t[l15] with t[16+l15].
// Result = sum over all 4 quads, uniform across the wave for each l15.
__device__ inline float quad_reduce_sum(float x) {
    union { float f; unsigned u; } c; c.f = x;
    uiv2_t s = __builtin_amdgcn_permlane32_swap(c.u, c.u, false, false);
    union { unsigned u; float f; } a0, a1;
    a0.u = s[0]; a1.u = s[1];
    float t = a0.f + a1.f;
    union { float f; unsigned u; } d; d.f = t;
    uiv2_t s2 = __builtin_amdgcn_permlane16_swap(d.u, d.u, false, false);
    union { unsigned u; float f; } b0, b1;
    b0.u = s2[0]; b1.u = s2[1];
    return b0.f + b1.f;
}

// ---------------------------------------------------------------------------
// Fused prep: one launch replaces {xconv, rope_tab, Wqkv-transpose,
// Wproj-transpose}. Block-uniform branch on blockIdx ranges.
//   [0, 8192)          xconv: x f32 -> bf16, 4 el/thread
//   [8192, 9216)       rope table: tab[token][0..31]=cos, [32..63]=sin
//   [9216, 12288)      Wqkv^T  (1024x3072 -> 3072x1024 bf16)
//   [12288, 13312)     Wproj^T (1024x1024 -> 1024x1024 bf16)
// ---------------------------------------------------------------------------
__global__ __launch_bounds__(256)
void prep_kernel(const float* __restrict__ x, __hip_bfloat16* __restrict__ xbf,
                 const int* __restrict__ keep, const int* __restrict__ orig,
                 float* __restrict__ tab,
                 const float* __restrict__ Wqkv, __hip_bfloat16* __restrict__ WqkvT,
                 const float* __restrict__ Wproj, __hip_bfloat16* __restrict__ WprojT) {
    __shared__ float s[32][33];
    const int bid = blockIdx.x;
    const int tid = threadIdx.x;

    if (bid < 8192) {
        int i = bid * 256 + tid;
        float4 v = *(const float4*)(x + (size_t)i * 4);
        uint2 u;
        u.x = pack2bf(v.x, v.y);
        u.y = pack2bf(v.z, v.w);
        *(uint2*)(xbf + (size_t)i * 4) = u;
    } else if (bid < 9216) {
        int i = (bid - 8192) * 256 + tid;
        int tok = i >> 5, d = i & 31;
        float freq = 0.5f * exp2f((float)d * (6.321928094887362f / 31.0f));
        float ang  = 6.283185307179586f * ((float)keep[tok] / (float)(*orig)) * freq;
        tab[(size_t)tok * 64 + d]      = cosf(ang);
        tab[(size_t)tok * 64 + 32 + d] = sinf(ang);
    } else {
        const float* in;
        __hip_bfloat16* outp;
        int N, n0, k0, r;
        if (bid < 12288) {
            r = bid - 9216;                 // Wqkv: grid (96, 32)
            in = Wqkv; outp = WqkvT; N = 3 * C_;
            n0 = (r % 96) * 32; k0 = (r / 96) * 32;
        } else {
            r = bid - 12288;                // Wproj: grid (32, 32)
            in = Wproj; outp = WprojT; N = C_;
            n0 = (r % 32) * 32; k0 = (r / 32) * 32;
        }
        const int K = C_;
        const int tx = tid & 31;
        const int ty = tid >> 5;            // 0..7
#pragma unroll
        for (int yy = 0; yy < 32; yy += 8)
            s[ty + yy][tx] = in[(size_t)(k0 + ty + yy) * N + n0 + tx];
        __syncthreads();
#pragma unroll
        for (int yy = 0; yy < 32; yy += 8)
            outp[(size_t)(n0 + ty + yy) * K + k0 + tx] = __float2bfloat16(s[tx][ty + yy]);
    }
}

// ---------------------------------------------------------------------------
// GEMM 256x128 tile, 8 waves (512 thr), BK=32, TRIPLE-BUFFERED staging with
// ONE barrier per K-step (round-9 structure, unchanged):
//   vmcnt(3|0) -> barrier -> issue tile t+2 -> compute tile t
// LDS 72 KB, 2 blocks/CU, LDS XOR swizzle (T2, both-sides).
// MODE 0: f32 store. MODE 1: qkv epilogue; V transposed through LDS in
// two 128-token passes.
// ---------------------------------------------------------------------------
#define ATILE (256 * 32)
#define BTILE (128 * 32)

template <int MODE>
__global__ __launch_bounds__(512)
void gemm_kernel(const __hip_bfloat16* __restrict__ A,
                 const __hip_bfloat16* __restrict__ BT,
                 const float* __restrict__ bias,
                 float* __restrict__ out,
                 __hip_bfloat16* __restrict__ qbuf,
                 __hip_bfloat16* __restrict__ kbuf,
                 __hip_bfloat16* __restrict__ vtbuf,
                 const float* __restrict__ ropetab,
                 int M, int N, int K) {
    // [0..3*ATILE): A triple-buffer; [3*ATILE..): B triple-buffer. 72 KB.
    __shared__ __align__(16) __hip_bfloat16 GS[3 * ATILE + 3 * BTILE];

    const int tid  = threadIdx.x;
    const int lane = tid & 63;
    const int wave = tid >> 6;          // 0..7
    const int wm   = wave >> 1;         // 0..3 (m quadrant)
    const int wn   = wave & 1;          // 0..1 (n half)
    const int l15  = lane & 15;
    const int quad = lane >> 4;

    const int nT  = N >> 7;
    const int grp = blockIdx.x / (8 * nT);
    const int rem = blockIdx.x - grp * 8 * nT;
    const int m0  = (grp * 8 + (rem & 7)) * 256;
    const int n0  = (rem >> 3) * 128;

    f32x4_t acc[4][4];
#pragma unroll
    for (int i = 0; i < 4; i++)
#pragma unroll
        for (int j = 0; j < 4; j++) acc[i][j] = (f32x4_t)0.0f;

    const int lrow = lane >> 2;
    // pre-swizzled source chunk: LDS[row][p] holds global chunk p^((row>>2)&3)
    const int scol = ((lane & 3) ^ ((lane >> 4) & 3)) * 8;
    const __hip_bfloat16* gA  = A  + (size_t)(m0 + wave * 32 + lrow) * K + scol;
    const __hip_bfloat16* gA2 = gA + (size_t)16 * K;
    const __hip_bfloat16* gB  = BT + (size_t)(n0 + wave * 16 + lrow) * K + scol;
    const int ldsA = wave * 32 * 32;   // this wave's A rows (elements)
    const int ldsB = wave * 16 * 32;   // this wave's B rows (elements)

    const int NK = K >> 5;
    // prologue: stage K-tiles 0,1 into buffers 0,1
    GLOAD_LDS16(gA,  GS + ldsA);
    GLOAD_LDS16(gA2, GS + ldsA + 16 * 32);
    GLOAD_LDS16(gB,  GS + 3 * ATILE + ldsB);
    if (NK > 1) {
        GLOAD_LDS16(gA  + 32, GS + ATILE + ldsA);
        GLOAD_LDS16(gA2 + 32, GS + ATILE + ldsA + 16 * 32);
        GLOAD_LDS16(gB  + 32, GS + 3 * ATILE + BTILE + ldsB);
    }

    int cur = 0;   // buffer slot of tile t
    int pre = 2;   // buffer slot of tile t+2
    for (int t = 0; t < NK; ++t) {
        if (t + 1 < NK) {
            // tile t drained; tile t+1's 3 loads may remain in flight
            asm volatile("s_waitcnt vmcnt(3)" ::: "memory");
        } else {
            asm volatile("s_waitcnt vmcnt(0)" ::: "memory");
        }
        __builtin_amdgcn_s_barrier();            // iter t-1 reads complete everywhere
        __builtin_amdgcn_sched_barrier(0);       // pin: nothing hoists above

        if (t + 2 < NK) {
            const int kk = (t + 2) << 5;
            GLOAD_LDS16(gA  + kk, GS + pre * ATILE + ldsA);
            GLOAD_LDS16(gA2 + kk, GS + pre * ATILE + ldsA + 16 * 32);
            GLOAD_LDS16(gB  + kk, GS + 3 * ATILE + pre * BTILE + ldsB);
            __builtin_amdgcn_sched_barrier(0);   // pin: DMA issues stay early
        }

        const int Ab = cur * ATILE;
        const int Bb = 3 * ATILE + cur * BTILE;
        bf16x8_t af[4], bfv[4];
#pragma unroll
        for (int i = 0; i < 4; i++)
            af[i] = *(const bf16x8_t*)(GS + Ab + (wm * 64 + i * 16 + l15) * 32 +
                                       ((quad ^ (l15 >> 2)) * 8));
#pragma unroll
        for (int j = 0; j < 4; j++)
            bfv[j] = *(const bf16x8_t*)(GS + Bb + (wn * 64 + j * 16 + l15) * 32 +
                                        ((quad ^ (l15 >> 2)) * 8));
#pragma unroll
        for (int i = 0; i < 4; i++)
#pragma unroll
            for (int j = 0; j < 4; j++)
                acc[i][j] = __builtin_amdgcn_mfma_f32_16x16x32_bf16(af[i], bfv[j], acc[i][j], 0, 0, 0);

        cur = (cur == 2) ? 0 : cur + 1;
        pre = (pre == 2) ? 0 : pre + 1;
    }

    float bv[4];
#pragma unroll
    for (int j = 0; j < 4; j++)
        bv[j] = bias[n0 + wn * 64 + j * 16 + l15];

    if (MODE == 0) {
#pragma unroll
        for (int i = 0; i < 4; i++)
#pragma unroll
            for (int r = 0; r < 4; r++) {
                int row = m0 + wm * 64 + i * 16 + quad * 4 + r;
#pragma unroll
                for (int j = 0; j < 4; j++) {
                    int col = n0 + wn * 64 + j * 16 + l15;
                    out[(size_t)row * N + col] = acc[i][j][r] + bv[j];
                }
            }
    } else {
        const int cb   = n0 + wn * 64;
        const int part = cb >> 10;           // 0=q 1=k 2=v  (uniform per block:
                                             // n0 is a multiple of 128, so no
                                             // block straddles the 1024/2048
                                             // boundaries)
        if (part == 2) {
            // V: transpose 256 tokens x 128 d (2 heads) through LDS in two
            // 128-token passes; region L=[128 d][136] (pad) fits 72KB GS.
            __syncthreads();                     // loop has no tail barrier:
                                                 // wait all waves' last reads
            const int hb = (n0 & 1023) >> 6;     // even head base
            const int bb = m0 >> 11;
            const int t0 = m0 & 2047;            // multiple of 256
            __hip_bfloat16* L = GS;
#pragma unroll
            for (int p = 0; p < 2; ++p) {
                if ((wm >> 1) == p) {            // waves owning this 128-token half
#pragma unroll
                    for (int j = 0; j < 4; j++) {
                        int d = wn * 64 + j * 16 + l15;
#pragma unroll
                        for (int i = 0; i < 4; i++) {
                            int rtb = (wm & 1) * 64 + i * 16 + quad * 4;
                            uint2 pk;
                            pk.x = pack2bf(acc[i][j][0] + bv[j], acc[i][j][1] + bv[j]);
                            pk.y = pack2bf(acc[i][j][2] + bv[j], acc[i][j][3] + bv[j]);
                            *(uint2*)(L + d * 136 + rtb) = pk;
                        }
                    }
                }
                __syncthreads();
                {
                    int row = tid >> 2;          // 0..127 = (head-off<<6)|dd
                    int hb2 = hb + (row >> 6);
                    int dd  = row & 63;
                    const __hip_bfloat16* src = L + row * 136;
                    __hip_bfloat16* dstv = vtbuf +
                        ((size_t)((bb * H_ + hb2) * D_ + dd)) * T_ + t0 + p * 128;
#pragma unroll
                    for (int s2 = 0; s2 < 4; s2++) {
                        int ch = (tid & 3) + s2 * 4;
                        *(bf16x8_t*)(dstv + ch * 8) = *(const bf16x8_t*)(src + ch * 8);
                    }
                }
                if (p == 0) __syncthreads();     // WAR before pass-1 L writes
            }
        } else {
            const int h = (cb & 1023) >> 6;
            __hip_bfloat16* dst = (part == 0) ? qbuf : kbuf;
            // q: fold 1/sqrt(D) AND log2(e) so attention uses exp2 directly
            const float sc = (part == 0) ? 0.18033688011112042f : 1.0f;
#pragma unroll
            for (int i = 0; i < 4; i++) {
#pragma unroll
                for (int r = 0; r < 4; r++) {
                    int row = m0 + wm * 64 + i * 16 + quad * 4 + r;
                    int b = row >> 11;
                    int t = row & 2047;
                    const float* trow = ropetab + (size_t)row * 64;
                    size_t base = ((size_t)(b * H_ + h) * T_ + t) * D_;
#pragma unroll
                    for (int j = 0; j < 2; j++) {
                        int d = j * 16 + l15;
                        float cs = trow[d];
                        float sn = trow[32 + d];
                        float x1 = acc[i][j][r]     + bv[j];
                        float x2 = acc[i][j + 2][r] + bv[j + 2];
                        dst[base + d]      = __float2bfloat16(sc * (x1 * cs - x2 * sn));
                        dst[base + d + 32] = __float2bfloat16(sc * (x1 * sn + x2 * cs));
                    }
                }
            }
        }
    }
}

// ---------------------------------------------------------------------------
// Flash attention v12: v11 (8 waves, quad-ring K/V, 1 barrier/tile) with the
// row-sum EVICTED FROM THE MATRIX PIPE. Arithmetic: attn MFMA work incl the
// ones-MFMA rowsum = 154.6 GF = 74.5 µs at the 2075 TF 16x16 ceiling, vs
// 84.2 µs measured -> 88% of roofline; the 4 rowsum MFMAs/iter are 1/9 of
// all matrix issues. Each lane already holds its 16 p-values in f32 regs,
// so: 16 VALU adds/qf per iter -> scalar accumulator; cross-quad reduction
// deferred to the epilogue (permlane32_swap + permlane16_swap self-swap:
// t is 32-periodic, result uniform across quads). VALU at 56% absorbs the
// +32 adds/iter. Numerics: sums f32 p instead of bf16-rounded p (~2^-12
// relative shift, inside the 2^-9 absmax band).
// ---------------------------------------------------------------------------
#define KVT 4096   // one 64x64 bf16 tile (elements)

__global__ __launch_bounds__(512, 4)
void attn_kernel(const __hip_bfloat16* __restrict__ q,
                 const __hip_bfloat16* __restrict__ k,
                 const __hip_bfloat16* __restrict__ vt,
                 __hip_bfloat16* __restrict__ attn_out) {
    // [0..4*KVT): K ring; [4*KVT..8*KVT): V ring (64 KB total).
    // After the loop (+syncthreads) the front is reused as the per-wave
    // epilogue staging area (8 waves x 32 x 72 bf16 = 36 KB <= 64 KB).
    __shared__ __align__(16) __hip_bfloat16 SMEM[8 * KVT];

    const int tid  = threadIdx.x;
    const int lane = tid & 63;
    const int wave = tid >> 6;           // 0..7
    const int l15  = lane & 15;
    const int quad = lane >> 4;
    const int x7   = l15 & 7;

    const int bh = blockIdx.x & 63;          // XCD swizzle (same-XCD per head)
    const int qt = blockIdx.x >> 6;          // 0..7
    const int b  = bh >> 4;
    const int h  = bh & 15;

    const size_t qkbase = (size_t)bh * T_ * D_;
    const size_t vbase  = (size_t)bh * D_ * T_;
    const int    qrow0  = qt * 256 + wave * 32;

    // DMA lane mapping: lane = drow*8 + dchunk; fetch global chunk dchunk^drow
    const int drow   = lane >> 3;        // 0..7
    const int gchunk = (lane & 7) ^ drow;
    const int r      = wave * 8;         // this wave's 8 rows of the 64-row tile

    const __hip_bfloat16* kg = k + qkbase;
    const __hip_bfloat16* vg = vt + vbase;

    // fragment-read swizzled chunk offsets (elements)
    const int c0 = ((quad)     ^ x7) * 8;
    const int c1 = ((4 + quad) ^ x7) * 8;

    // Q as B-fragment (n=qrow, k=d), direct global (once)
    bf16x8_t qa[2][2];
#pragma unroll
    for (int qf = 0; qf < 2; qf++)
#pragma unroll
        for (int kk = 0; kk < 2; kk++)
            qa[qf][kk] = *(const bf16x8_t*)(q + qkbase +
                          (size_t)(qrow0 + qf * 16 + l15) * D_ + kk * 32 + quad * 8);

    // loop-invariant C-operand: folds the -SHIFT2 softmax bias into the MFMA
    const f32x4_t mbias = (f32x4_t)(-SHIFT2);

    f32x4_t o[2][4];
#pragma unroll
    for (int qf = 0; qf < 2; qf++)
#pragma unroll
        for (int jd = 0; jd < 4; jd++) o[qf][jd] = (f32x4_t)0.0f;
    // per-lane partial row-sums (this lane's 16 keys per qf); cross-quad
    // reduction deferred to the epilogue
    float osv[2] = {0.0f, 0.0f};

    // prologue: stage tiles 0,1,2 into ring slots 0,1,2 (2 loads/wave each)
#pragma unroll
    for (int tt = 0; tt < 3; ++tt) {
        GLOAD_LDS16(kg + (size_t)(tt * 64 + r + drow) * D_ + gchunk * 8,
                    SMEM + tt * KVT + r * 64);
        GLOAD_LDS16(vg + (size_t)(r + drow) * T_ + tt * 64 + gchunk * 8,
                    SMEM + 4 * KVT + tt * KVT + r * 64);
    }

    const int NT = T_ / 64;   // 32
    for (int kt = 0; kt < NT; kt++) {
        // tile kt landed; kt+1/kt+2 (2 loads each) may remain in flight
        if (kt + 2 < NT) {
            asm volatile("s_waitcnt vmcnt(4)" ::: "memory");
        } else if (kt + 1 < NT) {
            asm volatile("s_waitcnt vmcnt(2)" ::: "memory");
        } else {
            asm volatile("s_waitcnt vmcnt(0)" ::: "memory");
        }
        __builtin_amdgcn_s_barrier();            // iter kt-1 reads complete everywhere
        __builtin_amdgcn_sched_barrier(0);       // pin: nothing hoists above

        // issue tile kt+3 -> slot (kt+3)%4 (= slot kt-1, read at iter kt-1)
        if (kt + 3 < NT) {
            const int slot = (kt + 3) & 3;
            GLOAD_LDS16(kg + (size_t)((kt + 3) * 64 + r + drow) * D_ + gchunk * 8,
                        SMEM + slot * KVT + r * 64);
            GLOAD_LDS16(vg + (size_t)(r + drow) * T_ + (kt + 3) * 64 + gchunk * 8,
                        SMEM + 4 * KVT + slot * KVT + r * 64);
            __builtin_amdgcn_sched_barrier(0);   // pin: DMA issues stay early
        }

        const __hip_bfloat16* KLc = SMEM + (kt & 3) * KVT;
        const __hip_bfloat16* VLc = SMEM + 4 * KVT + (kt & 3) * KVT;

        // K fragments (swizzled), then S^T = K.Q^T - SHIFT2 (bias via C-in)
        bf16x8_t kf[4][2];
#pragma unroll
        for (int jt = 0; jt < 4; jt++) {
            kf[jt][0] = *(const bf16x8_t*)(KLc + (jt * 16 + l15) * 64 + c0);
            kf[jt][1] = *(const bf16x8_t*)(KLc + (jt * 16 + l15) * 64 + c1);
        }

        f32x4_t sT[2][4];
        __builtin_amdgcn_s_setprio(1);
#pragma unroll
        for (int jt = 0; jt < 4; jt++)
#pragma unroll
            for (int qf = 0; qf < 2; qf++) {
                sT[qf][jt] = __builtin_amdgcn_mfma_f32_16x16x32_bf16(
                    kf[jt][0], qa[qf][0], mbias, 0, 0, 0);
                sT[qf][jt] = __builtin_amdgcn_mfma_f32_16x16x32_bf16(
                    kf[jt][1], qa[qf][1], sT[qf][jt], 0, 0, 0);
            }
        __builtin_amdgcn_s_setprio(0);

        // p = exp2(s'); accumulate this lane's 16-key partial row-sum on the
        // VALU (f32), pack to bf16 pairs, build P^T B-fragments via permlane
        // swaps (no LDS round-trip).
        bf16x8_t pb[2][2];
#pragma unroll
        for (int qf = 0; qf < 2; qf++) {
            unsigned int w0[4], w1[4];
            float ps = 0.0f;
#pragma unroll
            for (int jt = 0; jt < 4; jt++) {
                float p0 = __builtin_amdgcn_exp2f(sT[qf][jt][0]);
                float p1 = __builtin_amdgcn_exp2f(sT[qf][jt][1]);
                float p2 = __builtin_amdgcn_exp2f(sT[qf][jt][2]);
                float p3 = __builtin_amdgcn_exp2f(sT[qf][jt][3]);
                w0[jt] = pack2bf(p0, p1);   // keys quad*4+0, +1
                w1[jt] = pack2bf(p2, p3);   // keys quad*4+2, +3
                ps += (p0 + p1) + (p2 + p3);
            }
            osv[qf] += ps;
#pragma unroll
            for (int kk = 0; kk < 2; kk++) {
                uiv2_t s0 = __builtin_amdgcn_permlane32_swap(w0[2 * kk], w0[2 * kk + 1], false, false);
                uiv2_t r0 = __builtin_amdgcn_permlane16_swap(s0[0], s0[1], false, false);
                uiv2_t s1 = __builtin_amdgcn_permlane32_swap(w1[2 * kk], w1[2 * kk + 1], false, false);
                uiv2_t r1 = __builtin_amdgcn_permlane16_swap(s1[0], s1[1], false, false);
                union { unsigned int u[4]; bf16x8_t v; } pu;
                pu.u[0] = r0[0];   // keys +0,1
                pu.u[1] = r1[0];   // keys +2,3
                pu.u[2] = r0[1];   // keys +4,5
                pu.u[3] = r1[1];   // keys +6,7
                pb[qf][kk] = pu.v;
            }
        }

        __builtin_amdgcn_s_setprio(1);
        // o^T += V^T.P^T
#pragma unroll
        for (int jd = 0; jd < 4; jd++) {
            bf16x8_t vf0 = *(const bf16x8_t*)(VLc + (jd * 16 + l15) * 64 + c0);
            bf16x8_t vf1 = *(const bf16x8_t*)(VLc + (jd * 16 + l15) * 64 + c1);
#pragma unroll
            for (int qf = 0; qf < 2; qf++) {
                o[qf][jd] = __builtin_amdgcn_mfma_f32_16x16x32_bf16(vf0, pb[qf][0], o[qf][jd], 0, 0, 0);
                o[qf][jd] = __builtin_amdgcn_mfma_f32_16x16x32_bf16(vf1, pb[qf][1], o[qf][jd], 0, 0, 0);
            }
        }
        __builtin_amdgcn_s_setprio(0);
        // no tail barrier: next iter's vmcnt+barrier provides the sync
    }

    // cross-quad reduction (once): full 64-key row-sums, uniform per l15
    float inv[2];
    inv[0] = 1.0f / quad_reduce_sum(osv[0]);
    inv[1] = 1.0f / quad_reduce_sum(osv[1]);

    // epilogue staging: wait for all waves' last-tile reads before
    // overwriting the K/V ring
    __syncthreads();
    __hip_bfloat16* Pep = SMEM + wave * (32 * 72);

    // o^T -> LDS (packed b64), then coalesced 16B store
#pragma unroll
    for (int qf = 0; qf < 2; qf++) {
#pragma unroll
        for (int jd = 0; jd < 4; jd++) {
            uint2 pk;
            pk.x = pack2bf(o[qf][jd][0] * inv[qf], o[qf][jd][1] * inv[qf]);
            pk.y = pack2bf(o[qf][jd][2] * inv[qf], o[qf][jd][3] * inv[qf]);
            *(uint2*)(Pep + (qf * 16 + l15) * 72 + jd * 16 + quad * 4) = pk;
        }
    }
    WAVE_ORDER();

#pragma unroll
    for (int rnd = 0; rnd < 4; rnd++) {
        int row = rnd * 8 + (lane >> 3);
        int col = (lane & 7) * 8;
        bf16x8_t vrow = *(const bf16x8_t*)(Pep + row * 72 + col);
        int token = qt * 256 + wave * 32 + row;
        *(bf16x8_t*)(attn_out + ((size_t)(b * T_ + token)) * C_ + h * 64 + col) = vrow;
    }
}

// ---------------------------------------------------------------------------
extern "C" void kernel_launch(void* const* d_in, const int* in_sizes, int n_in,
                              void* d_out, int out_size, void* d_ws, size_t ws_size,
                              hipStream_t stream) {
    const float* x        = (const float*)d_in[0];
    const int*   keep_idx = (const int*)d_in[1];
    const int*   orig_len = (const int*)d_in[2];
    const float* Wqkv     = (const float*)d_in[3];
    const float* bqkv     = (const float*)d_in[4];
    const float* Wproj    = (const float*)d_in[5];
    const float* bproj    = (const float*)d_in[6];
    float*       out      = (float*)d_out;

    const size_t NTOK = (size_t)B_ * T_;
    const size_t QKV1 = NTOK * C_;

    __hip_bfloat16* qbuf    = (__hip_bfloat16*)d_ws;
    __hip_bfloat16* kbuf    = qbuf    + QKV1;
    __hip_bfloat16* vtbuf   = kbuf    + QKV1;
    __hip_bfloat16* attnbuf = vtbuf   + QKV1;
    __hip_bfloat16* WqkvT   = attnbuf + QKV1;
    __hip_bfloat16* WprojT  = WqkvT   + (size_t)C_ * 3 * C_;
    __hip_bfloat16* xbf     = WprojT  + (size_t)C_ * C_;
    float*          ropetab = (float*)(xbf + QKV1);

    // fused prep: xconv (8192) + rope (1024) + WqkvT (3072) + WprojT (1024)
    prep_kernel<<<13312, 256, 0, stream>>>(x, xbf, keep_idx, orig_len, ropetab,
                                           Wqkv, WqkvT, Wproj, WprojT);

    gemm_kernel<1><<<(8192 / 256) * (3072 / 128), 512, 0, stream>>>(
        xbf, WqkvT, bqkv, nullptr, qbuf, kbuf, vtbuf, ropetab, 8192, 3072, 1024);

    attn_kernel<<<(T_ / 256) * 64, 512, 0, stream>>>(qbuf, kbuf, vtbuf, attnbuf);

    gemm_kernel<0><<<(8192 / 256) * (1024 / 128), 512, 0, stream>>>(
        attnbuf, WprojT, bproj, out, nullptr, nullptr, nullptr, nullptr, 8192, 1024, 1024);
}